// Round 1
// baseline (1040.661 us; speedup 1.0000x reference)
//
#include <hip/hip_runtime.h>
#include <math.h>

typedef long long ll;

#define FIN 128
#define HID 256
#define FOUT 40

// ---------------------------------------------------------------------------
// edge_index may arrive as int64 (jnp.int64 w/ x64 enabled) or int32
// (canonicalized). Detect on device: for int64 data the high words are 0.
// ---------------------------------------------------------------------------
__device__ __forceinline__ int edge_val(const void* ei, ll idx, int is64) {
  return is64 ? (int)((const ll*)ei)[idx] : ((const int*)ei)[idx];
}

__global__ void k_detect(const unsigned* __restrict__ ei, int* __restrict__ flag) {
  // values < 100000 << 2^32; odd words all zero => int64 layout
  flag[0] = (ei[1] == 0u && ei[3] == 0u && ei[5] == 0u && ei[7] == 0u) ? 1 : 0;
}

__global__ void k_zero(int* __restrict__ p, int n) {
  int i = blockIdx.x * 256 + threadIdx.x;
  if (i < n) p[i] = 0;
}

__global__ void k_count(const void* __restrict__ ei, const int* __restrict__ flag,
                        int* __restrict__ cnt, ll E) {
  ll e = (ll)blockIdx.x * 256 + threadIdx.x;
  if (e < E) {
    int is64 = flag[0];
    int dst = edge_val(ei, E + e, is64);
    atomicAdd(&cnt[dst], 1);
  }
}

// -------------------- exclusive prefix scan over counts --------------------
__global__ __launch_bounds__(1024) void k_scan1(const int* __restrict__ cnt,
                                                int* __restrict__ row_off,
                                                int* __restrict__ blksums, int n) {
  __shared__ int sm[1024];
  int t = threadIdx.x;
  int base = blockIdx.x * 4096 + t * 4;
  int v0 = (base + 0 < n) ? cnt[base + 0] : 0;
  int v1 = (base + 1 < n) ? cnt[base + 1] : 0;
  int v2 = (base + 2 < n) ? cnt[base + 2] : 0;
  int v3 = (base + 3 < n) ? cnt[base + 3] : 0;
  int s = v0 + v1 + v2 + v3;
  sm[t] = s;
  __syncthreads();
  for (int off = 1; off < 1024; off <<= 1) {
    int u = (t >= off) ? sm[t - off] : 0;
    __syncthreads();
    sm[t] += u;
    __syncthreads();
  }
  int excl = sm[t] - s;
  if (base + 0 < n) row_off[base + 0] = excl;
  if (base + 1 < n) row_off[base + 1] = excl + v0;
  if (base + 2 < n) row_off[base + 2] = excl + v0 + v1;
  if (base + 3 < n) row_off[base + 3] = excl + v0 + v1 + v2;
  if (t == 1023) blksums[blockIdx.x] = sm[1023];
}

__global__ void k_scan2(int* __restrict__ blksums, int nb) {
  if (threadIdx.x == 0 && blockIdx.x == 0) {
    int acc = 0;
    for (int i = 0; i < nb; ++i) { int v = blksums[i]; blksums[i] = acc; acc += v; }
    blksums[nb] = acc;  // total == E
  }
}

__global__ void k_scan3(int* __restrict__ row_off, int* __restrict__ cursor,
                        const int* __restrict__ blksums, int n, int nb) {
  int i = blockIdx.x * 1024 + threadIdx.x;
  if (i < n) {
    int v = row_off[i] + blksums[i >> 12];
    row_off[i] = v;
    cursor[i] = v;  // running cursor for bucket fill
  }
  if (i == 0) row_off[n] = blksums[nb];
}

__global__ void k_dis(const int* __restrict__ row_off, float* __restrict__ dis, int n) {
  int i = blockIdx.x * 256 + threadIdx.x;
  if (i < n) dis[i] = rsqrtf((float)(row_off[i + 1] - row_off[i]) + 1.0f);
}

__global__ void k_fill(const void* __restrict__ ei, const int* __restrict__ flag,
                       int* __restrict__ cursor, int* __restrict__ csr, ll E) {
  ll e = (ll)blockIdx.x * 256 + threadIdx.x;
  if (e < E) {
    int is64 = flag[0];
    int src = edge_val(ei, e, is64);
    int dst = edge_val(ei, E + e, is64);
    int pos = atomicAdd(&cursor[dst], 1);
    csr[pos] = src;
  }
}

// ---------------------------------------------------------------------------
// Fused layer 1: per 16-node tile:
//   P1: agg = dis_i^2 * x_i + sum_e dis_i*dis_s * x_s   -> LDS [16][132]
//   P2: 4x4-microtile GEMM (agg @ W1), W1 streamed from L2
//   P3: +b1, ReLU -> LDS h tile [16][260]
//   P4: h @ W2 (W2 staged in LDS, [k/4][col][k%4] layout) -> xw2 global
// LDS: 40KB (w2s) + 16.6KB (sm union) = 56.6KB -> 2 blocks/CU
// ---------------------------------------------------------------------------
__global__ __launch_bounds__(256) void k_layer1(
    const float* __restrict__ x, const int* __restrict__ csr,
    const int* __restrict__ row_off, const float* __restrict__ dis,
    const float* __restrict__ W1, const float* __restrict__ b1,
    const float* __restrict__ W2, float* __restrict__ xw2, int n)
{
  __shared__ __align__(16) float w2s[64 * 160];     // 40KB
  __shared__ __align__(16) float sm[16 * 260];      // 16.25KB union: xs[16][132] / h[16][260]

  int tid = threadIdx.x;

  // stage W2 -> LDS, layout [k>>2][col][k&3] so k-vectorized reads are float4
  for (int i = tid; i < HID * FOUT; i += 256) {
    int k = i / FOUT;
    int c = i - k * FOUT;
    w2s[(k >> 2) * 160 + c * 4 + (k & 3)] = W2[i];
  }

  // ---- P1: aggregate x over incoming edges (wave per node, float2 lanes) ----
  int n0 = blockIdx.x * 16;
  int wv = tid >> 6, lane = tid & 63;
  for (int j = 0; j < 4; ++j) {
    int nl = wv * 4 + j;
    int node = n0 + nl;
    float ax = 0.f, ay = 0.f;
    if (node < n) {
      float di = dis[node];
      float2 v = ((const float2*)(x + (size_t)node * FIN))[lane];
      ax = di * di * v.x;
      ay = di * di * v.y;
      int e0 = row_off[node], e1 = row_off[node + 1];
      for (int e = e0; e < e1; ++e) {
        int s = csr[e];
        float w = di * dis[s];
        float2 u = ((const float2*)(x + (size_t)s * FIN))[lane];
        ax += w * u.x;
        ay += w * u.y;
      }
    }
    sm[nl * 132 + lane * 2]     = ax;
    sm[nl * 132 + lane * 2 + 1] = ay;
  }
  __syncthreads();

  // ---- P2: GEMM agg[16x128] @ W1[128x256], 4 nodes x 4 cols per thread ----
  int tx = tid & 63, ty = tid >> 6;
  float4 a0 = {0,0,0,0}, a1 = {0,0,0,0}, a2 = {0,0,0,0}, a3 = {0,0,0,0};
  #pragma unroll 4
  for (int k = 0; k < FIN; ++k) {
    float4 w = *(const float4*)(W1 + (size_t)k * HID + tx * 4);
    float x0 = sm[(ty * 4 + 0) * 132 + k];
    float x1 = sm[(ty * 4 + 1) * 132 + k];
    float x2 = sm[(ty * 4 + 2) * 132 + k];
    float x3 = sm[(ty * 4 + 3) * 132 + k];
    a0.x += x0 * w.x; a0.y += x0 * w.y; a0.z += x0 * w.z; a0.w += x0 * w.w;
    a1.x += x1 * w.x; a1.y += x1 * w.y; a1.z += x1 * w.z; a1.w += x1 * w.w;
    a2.x += x2 * w.x; a2.y += x2 * w.y; a2.z += x2 * w.z; a2.w += x2 * w.w;
    a3.x += x3 * w.x; a3.y += x3 * w.y; a3.z += x3 * w.z; a3.w += x3 * w.w;
  }
  __syncthreads();  // everyone done reading xs before we overwrite with h

  // ---- P3: bias + ReLU -> h tile in LDS [16][260] ----
  float4 bv = *(const float4*)(b1 + tx * 4);
  {
    float4 hs;
    hs.x = fmaxf(a0.x + bv.x, 0.f); hs.y = fmaxf(a0.y + bv.y, 0.f);
    hs.z = fmaxf(a0.z + bv.z, 0.f); hs.w = fmaxf(a0.w + bv.w, 0.f);
    *(float4*)(sm + (ty * 4 + 0) * 260 + tx * 4) = hs;
    hs.x = fmaxf(a1.x + bv.x, 0.f); hs.y = fmaxf(a1.y + bv.y, 0.f);
    hs.z = fmaxf(a1.z + bv.z, 0.f); hs.w = fmaxf(a1.w + bv.w, 0.f);
    *(float4*)(sm + (ty * 4 + 1) * 260 + tx * 4) = hs;
    hs.x = fmaxf(a2.x + bv.x, 0.f); hs.y = fmaxf(a2.y + bv.y, 0.f);
    hs.z = fmaxf(a2.z + bv.z, 0.f); hs.w = fmaxf(a2.w + bv.w, 0.f);
    *(float4*)(sm + (ty * 4 + 2) * 260 + tx * 4) = hs;
    hs.x = fmaxf(a3.x + bv.x, 0.f); hs.y = fmaxf(a3.y + bv.y, 0.f);
    hs.z = fmaxf(a3.z + bv.z, 0.f); hs.w = fmaxf(a3.w + bv.w, 0.f);
    *(float4*)(sm + (ty * 4 + 3) * 260 + tx * 4) = hs;
  }
  __syncthreads();

  // ---- P4: h[16x256] @ W2[256x40] -> xw2; thread = (node, col c0/c0+16/c0+32) ----
  int nn = tid >> 4, c0 = tid & 15;
  float acc0 = 0.f, acc1 = 0.f, acc2 = 0.f;
  #pragma unroll 4
  for (int k4 = 0; k4 < HID / 4; ++k4) {
    float4 hv = *(const float4*)(sm + nn * 260 + k4 * 4);
    float4 wa = *(const float4*)(w2s + k4 * 160 + c0 * 4);
    float4 wb = *(const float4*)(w2s + k4 * 160 + (c0 + 16) * 4);
    acc0 += hv.x * wa.x + hv.y * wa.y + hv.z * wa.z + hv.w * wa.w;
    acc1 += hv.x * wb.x + hv.y * wb.y + hv.z * wb.z + hv.w * wb.w;
    if (c0 < 8) {
      float4 wc = *(const float4*)(w2s + k4 * 160 + (c0 + 32) * 4);
      acc2 += hv.x * wc.x + hv.y * wc.y + hv.z * wc.z + hv.w * wc.w;
    }
  }
  ll nodeg = (ll)n0 + nn;
  if (nodeg < n) {
    float* o = xw2 + nodeg * FOUT;
    o[c0] = acc0;
    o[c0 + 16] = acc1;
    if (c0 < 8) o[c0 + 32] = acc2;
  }
}

// ---------------------------------------------------------------------------
// Layer 2 aggregation + bias + log_softmax. Wave per node, lane = class.
// ---------------------------------------------------------------------------
__global__ __launch_bounds__(256) void k_layer2(
    const float* __restrict__ xw2, const int* __restrict__ csr,
    const int* __restrict__ row_off, const float* __restrict__ dis,
    const float* __restrict__ b2, float* __restrict__ out, int n)
{
  int node = blockIdx.x * 4 + (threadIdx.x >> 6);
  int c = threadIdx.x & 63;
  if (node >= n) return;
  float di = dis[node];
  float acc = 0.f;
  if (c < FOUT) acc = di * di * xw2[(size_t)node * FOUT + c];
  int e0 = row_off[node], e1 = row_off[node + 1];
  for (int e = e0; e < e1; ++e) {
    int s = csr[e];
    float w = di * dis[s];
    if (c < FOUT) acc += w * xw2[(size_t)s * FOUT + c];
  }
  float logit = (c < FOUT) ? (acc + b2[c]) : -INFINITY;
  float m = logit;
  #pragma unroll
  for (int off = 32; off > 0; off >>= 1) m = fmaxf(m, __shfl_xor(m, off));
  float ex = (c < FOUT) ? expf(logit - m) : 0.f;
  float sum = ex;
  #pragma unroll
  for (int off = 32; off > 0; off >>= 1) sum += __shfl_xor(sum, off);
  if (c < FOUT) out[(size_t)node * FOUT + c] = logit - m - logf(sum);
}

// ---------------------------------------------------------------------------
extern "C" void kernel_launch(void* const* d_in, const int* in_sizes, int n_in,
                              void* d_out, int out_size, void* d_ws, size_t ws_size,
                              hipStream_t stream) {
  const float* x  = (const float*)d_in[0];
  const void*  ei = d_in[1];
  const float* W1 = (const float*)d_in[2];
  const float* b1 = (const float*)d_in[3];
  const float* W2 = (const float*)d_in[4];
  const float* b2 = (const float*)d_in[5];
  float* out = (float*)d_out;

  int n = in_sizes[0] / FIN;        // 100000
  ll  E = (ll)in_sizes[1] / 2;      // 1600000
  int nb = (n + 4095) / 4096;       // scan chunks

  // workspace carve-up (all 256B aligned); total ~= 24 MB
  char* ws = (char*)d_ws;
  size_t off = 0;
  auto carve = [&](size_t bytes) -> char* {
    char* p = ws + off;
    off = (off + bytes + 255) & ~(size_t)255;
    return p;
  };
  int*   flag    = (int*)carve(16);
  int*   row_off = (int*)carve((size_t)(n + 1) * 4);
  int*   cursor  = (int*)carve((size_t)n * 4);
  int*   csr     = (int*)carve((size_t)E * 4);
  int*   blksums = (int*)carve(64 * 4);
  float* dis     = (float*)carve((size_t)n * 4);
  float* xw2     = (float*)carve((size_t)n * FOUT * 4);
  (void)ws_size; (void)n_in; (void)out_size;

  int gn256 = (n + 255) / 256;
  int gE256 = (int)((E + 255) / 256);

  hipLaunchKernelGGL(k_detect, dim3(1), dim3(1), 0, stream, (const unsigned*)ei, flag);
  hipLaunchKernelGGL(k_zero,   dim3(gn256), dim3(256), 0, stream, cursor, n);
  hipLaunchKernelGGL(k_count,  dim3(gE256), dim3(256), 0, stream, ei, flag, cursor, E);
  hipLaunchKernelGGL(k_scan1,  dim3(nb), dim3(1024), 0, stream, cursor, row_off, blksums, n);
  hipLaunchKernelGGL(k_scan2,  dim3(1), dim3(1), 0, stream, blksums, nb);
  hipLaunchKernelGGL(k_scan3,  dim3((n + 1023) / 1024), dim3(1024), 0, stream,
                     row_off, cursor, blksums, n, nb);
  hipLaunchKernelGGL(k_dis,    dim3(gn256), dim3(256), 0, stream, row_off, dis, n);
  hipLaunchKernelGGL(k_fill,   dim3(gE256), dim3(256), 0, stream, ei, flag, cursor, csr, E);
  hipLaunchKernelGGL(k_layer1, dim3((n + 15) / 16), dim3(256), 0, stream,
                     x, csr, row_off, dis, W1, b1, W2, xw2, n);
  hipLaunchKernelGGL(k_layer2, dim3((n + 3) / 4), dim3(256), 0, stream,
                     xw2, csr, row_off, dis, b2, out, n);
}

// Round 2
// 584.714 us; speedup vs baseline: 1.7798x; 1.7798x over previous
//
#include <hip/hip_runtime.h>
#include <math.h>

typedef long long ll;

#define FIN 128
#define HID 256
#define FOUT 40

// ---------------------------------------------------------------------------
// edge_index may arrive as int64 (jnp.int64 w/ x64 enabled) or int32
// (canonicalized). Detect on device: for int64 data the high words are 0.
// ---------------------------------------------------------------------------
__device__ __forceinline__ int edge_val(const void* ei, ll idx, int is64) {
  return is64 ? (int)((const ll*)ei)[idx] : ((const int*)ei)[idx];
}

__global__ void k_detect(const unsigned* __restrict__ ei, int* __restrict__ flag) {
  flag[0] = (ei[1] == 0u && ei[3] == 0u && ei[5] == 0u && ei[7] == 0u) ? 1 : 0;
}

__global__ void k_zero(int* __restrict__ p, int n) {
  int i = blockIdx.x * 256 + threadIdx.x;
  if (i < n) p[i] = 0;
}

__global__ void k_count(const void* __restrict__ ei, const int* __restrict__ flag,
                        int* __restrict__ cnt, ll E) {
  ll e = (ll)blockIdx.x * 256 + threadIdx.x;
  if (e < E) {
    int is64 = flag[0];
    int dst = edge_val(ei, E + e, is64);
    atomicAdd(&cnt[dst], 1);
  }
}

// -------------------- exclusive prefix scan over counts --------------------
__global__ __launch_bounds__(1024) void k_scan1(const int* __restrict__ cnt,
                                                int* __restrict__ row_off,
                                                int* __restrict__ blksums, int n) {
  __shared__ int sm[1024];
  int t = threadIdx.x;
  int base = blockIdx.x * 4096 + t * 4;
  int v0 = (base + 0 < n) ? cnt[base + 0] : 0;
  int v1 = (base + 1 < n) ? cnt[base + 1] : 0;
  int v2 = (base + 2 < n) ? cnt[base + 2] : 0;
  int v3 = (base + 3 < n) ? cnt[base + 3] : 0;
  int s = v0 + v1 + v2 + v3;
  sm[t] = s;
  __syncthreads();
  for (int off = 1; off < 1024; off <<= 1) {
    int u = (t >= off) ? sm[t - off] : 0;
    __syncthreads();
    sm[t] += u;
    __syncthreads();
  }
  int excl = sm[t] - s;
  if (base + 0 < n) row_off[base + 0] = excl;
  if (base + 1 < n) row_off[base + 1] = excl + v0;
  if (base + 2 < n) row_off[base + 2] = excl + v0 + v1;
  if (base + 3 < n) row_off[base + 3] = excl + v0 + v1 + v2;
  if (t == 1023) blksums[blockIdx.x] = sm[1023];
}

__global__ void k_scan2(int* __restrict__ blksums, int nb) {
  if (threadIdx.x == 0 && blockIdx.x == 0) {
    int acc = 0;
    for (int i = 0; i < nb; ++i) { int v = blksums[i]; blksums[i] = acc; acc += v; }
    blksums[nb] = acc;  // total == E
  }
}

__global__ void k_scan3(int* __restrict__ row_off, int* __restrict__ cursor,
                        const int* __restrict__ blksums, int n, int nb) {
  int i = blockIdx.x * 1024 + threadIdx.x;
  if (i < n) {
    int v = row_off[i] + blksums[i >> 12];
    row_off[i] = v;
    cursor[i] = v;
  }
  if (i == 0) row_off[n] = blksums[nb];
}

__global__ void k_dis(const int* __restrict__ row_off, float* __restrict__ dis, int n) {
  int i = blockIdx.x * 256 + threadIdx.x;
  if (i < n) dis[i] = rsqrtf((float)(row_off[i + 1] - row_off[i]) + 1.0f);
}

__global__ void k_fill(const void* __restrict__ ei, const int* __restrict__ flag,
                       int* __restrict__ cursor, int* __restrict__ csr, ll E) {
  ll e = (ll)blockIdx.x * 256 + threadIdx.x;
  if (e < E) {
    int is64 = flag[0];
    int src = edge_val(ei, e, is64);
    int dst = edge_val(ei, E + e, is64);
    int pos = atomicAdd(&cursor[dst], 1);
    csr[pos] = src;
  }
}

// ---------------------------------------------------------------------------
// k_agg1 (split path): per 16-node tile:
//   P1: quarter-wave (16 lanes x 32B) per node, 4 concurrent nodes/wave,
//       2x edge unroll -> 8 x-rows in flight per wave.  agg -> LDS [16][132]
//   P2: GEMM agg[16x128] @ W1[128x256] (+b1, ReLU) -> h global
// LDS = 8.4KB -> thread-capped occupancy (vs 22% for the old fused kernel)
// ---------------------------------------------------------------------------
__global__ __launch_bounds__(256) void k_agg1(
    const float* __restrict__ x, const int* __restrict__ csr,
    const int* __restrict__ row_off, const float* __restrict__ dis,
    const float* __restrict__ W1, const float* __restrict__ b1,
    float* __restrict__ h, int n)
{
  __shared__ __align__(16) float xs[16 * 132];
  int tid = threadIdx.x;
  int n0 = blockIdx.x * 16;
  int wv = tid >> 6, lane = tid & 63, qq = lane >> 4, l16 = lane & 15;
  int nl = wv * 4 + qq;
  int node = n0 + nl;

  float4 aA = {0,0,0,0}, aB = {0,0,0,0};
  if (node < n) {
    float di = dis[node];
    const float4* xr = (const float4*)(x + (size_t)node * FIN) + l16 * 2;
    float4 v0 = xr[0], v1 = xr[1];
    float dii = di * di;
    aA.x = dii * v0.x; aA.y = dii * v0.y; aA.z = dii * v0.z; aA.w = dii * v0.w;
    aB.x = dii * v1.x; aB.y = dii * v1.y; aB.z = dii * v1.z; aB.w = dii * v1.w;
    int e0 = row_off[node], e1 = row_off[node + 1];
    int e = e0;
    for (; e + 2 <= e1; e += 2) {
      int s0 = csr[e], s1 = csr[e + 1];
      float w0 = di * dis[s0], w1 = di * dis[s1];
      const float4* r0 = (const float4*)(x + (size_t)s0 * FIN) + l16 * 2;
      const float4* r1 = (const float4*)(x + (size_t)s1 * FIN) + l16 * 2;
      float4 p0 = r0[0], p1 = r0[1];
      float4 u0 = r1[0], u1 = r1[1];
      aA.x += w0 * p0.x; aA.y += w0 * p0.y; aA.z += w0 * p0.z; aA.w += w0 * p0.w;
      aB.x += w0 * p1.x; aB.y += w0 * p1.y; aB.z += w0 * p1.z; aB.w += w0 * p1.w;
      aA.x += w1 * u0.x; aA.y += w1 * u0.y; aA.z += w1 * u0.z; aA.w += w1 * u0.w;
      aB.x += w1 * u1.x; aB.y += w1 * u1.y; aB.z += w1 * u1.z; aB.w += w1 * u1.w;
    }
    if (e < e1) {
      int s0 = csr[e];
      float w0 = di * dis[s0];
      const float4* r0 = (const float4*)(x + (size_t)s0 * FIN) + l16 * 2;
      float4 p0 = r0[0], p1 = r0[1];
      aA.x += w0 * p0.x; aA.y += w0 * p0.y; aA.z += w0 * p0.z; aA.w += w0 * p0.w;
      aB.x += w0 * p1.x; aB.y += w0 * p1.y; aB.z += w0 * p1.z; aB.w += w0 * p1.w;
    }
  }
  *(float4*)(xs + nl * 132 + l16 * 8)     = aA;
  *(float4*)(xs + nl * 132 + l16 * 8 + 4) = aB;
  __syncthreads();

  // P2: 4 nodes x 4 cols per thread; W1 rows streamed (L2-resident, 131KB)
  int tx = tid & 63, ty = tid >> 6;
  float4 acc[4] = {{0,0,0,0},{0,0,0,0},{0,0,0,0},{0,0,0,0}};
  #pragma unroll 4
  for (int k = 0; k < FIN; ++k) {
    float4 w = *(const float4*)(W1 + (size_t)k * HID + tx * 4);
    #pragma unroll
    for (int j = 0; j < 4; ++j) {
      float xv = xs[(ty * 4 + j) * 132 + k];
      acc[j].x += xv * w.x; acc[j].y += xv * w.y;
      acc[j].z += xv * w.z; acc[j].w += xv * w.w;
    }
  }
  float4 bv = *(const float4*)(b1 + tx * 4);
  #pragma unroll
  for (int j = 0; j < 4; ++j) {
    int nodeg = n0 + ty * 4 + j;
    if (nodeg < n) {
      float4 o;
      o.x = fmaxf(acc[j].x + bv.x, 0.f);
      o.y = fmaxf(acc[j].y + bv.y, 0.f);
      o.z = fmaxf(acc[j].z + bv.z, 0.f);
      o.w = fmaxf(acc[j].w + bv.w, 0.f);
      *(float4*)(h + (size_t)nodeg * HID + tx * 4) = o;
    }
  }
}

// ---------------------------------------------------------------------------
// k_gemm2 (split path): h[n x 256] @ W2[256 x 40] -> xw2.  W2 staged once per
// block (40KB LDS, [k/4][col][k%4]); 4 subtiles of 16 nodes staged to LDS.
// Streaming, ~120MB total.
// ---------------------------------------------------------------------------
__global__ __launch_bounds__(256) void k_gemm2(
    const float* __restrict__ h, const float* __restrict__ W2,
    float* __restrict__ xw2, int n)
{
  __shared__ __align__(16) float w2s[64 * 160];   // 40KB
  __shared__ __align__(16) float hs[16 * 260];    // 16.25KB
  int tid = threadIdx.x;
  for (int i = tid; i < HID * FOUT; i += 256) {
    int k = i / FOUT;
    int c = i - k * FOUT;
    w2s[(k >> 2) * 160 + c * 4 + (k & 3)] = W2[i];
  }
  int n0 = blockIdx.x * 64;
  int nn = tid >> 4, c0 = tid & 15;
  for (int sub = 0; sub < 4; ++sub) {
    int base = n0 + sub * 16;
    __syncthreads();  // protect hs from previous subtile's readers (and w2s on sub=0)
    for (int i = tid; i < 1024; i += 256) {
      int r = i >> 6, cc = i & 63;
      float4 v = {0, 0, 0, 0};
      if (base + r < n) v = *(const float4*)(h + (size_t)(base + r) * HID + cc * 4);
      *(float4*)(hs + r * 260 + cc * 4) = v;
    }
    __syncthreads();
    float acc0 = 0.f, acc1 = 0.f, acc2 = 0.f;
    #pragma unroll 4
    for (int k4 = 0; k4 < HID / 4; ++k4) {
      float4 hv = *(const float4*)(hs + nn * 260 + k4 * 4);
      float4 wa = *(const float4*)(w2s + k4 * 160 + c0 * 4);
      float4 wb = *(const float4*)(w2s + k4 * 160 + (c0 + 16) * 4);
      acc0 += hv.x * wa.x + hv.y * wa.y + hv.z * wa.z + hv.w * wa.w;
      acc1 += hv.x * wb.x + hv.y * wb.y + hv.z * wb.z + hv.w * wb.w;
      if (c0 < 8) {
        float4 wc = *(const float4*)(w2s + k4 * 160 + (c0 + 32) * 4);
        acc2 += hv.x * wc.x + hv.y * wc.y + hv.z * wc.z + hv.w * wc.w;
      }
    }
    ll g = (ll)base + nn;
    if (g < n) {
      float* o = xw2 + g * FOUT;
      o[c0] = acc0;
      o[c0 + 16] = acc1;
      if (c0 < 8) o[c0 + 32] = acc2;
    }
  }
}

// ---------------------------------------------------------------------------
// Fused fallback (round-1 k_layer1) — used only if ws_size can't fit h.
// ---------------------------------------------------------------------------
__global__ __launch_bounds__(256) void k_layer1(
    const float* __restrict__ x, const int* __restrict__ csr,
    const int* __restrict__ row_off, const float* __restrict__ dis,
    const float* __restrict__ W1, const float* __restrict__ b1,
    const float* __restrict__ W2, float* __restrict__ xw2, int n)
{
  __shared__ __align__(16) float w2s[64 * 160];
  __shared__ __align__(16) float sm[16 * 260];
  int tid = threadIdx.x;
  for (int i = tid; i < HID * FOUT; i += 256) {
    int k = i / FOUT;
    int c = i - k * FOUT;
    w2s[(k >> 2) * 160 + c * 4 + (k & 3)] = W2[i];
  }
  int n0 = blockIdx.x * 16;
  int wv = tid >> 6, lane = tid & 63;
  for (int j = 0; j < 4; ++j) {
    int nl = wv * 4 + j;
    int node = n0 + nl;
    float ax = 0.f, ay = 0.f;
    if (node < n) {
      float di = dis[node];
      float2 v = ((const float2*)(x + (size_t)node * FIN))[lane];
      ax = di * di * v.x;
      ay = di * di * v.y;
      int e0 = row_off[node], e1 = row_off[node + 1];
      for (int e = e0; e < e1; ++e) {
        int s = csr[e];
        float w = di * dis[s];
        float2 u = ((const float2*)(x + (size_t)s * FIN))[lane];
        ax += w * u.x;
        ay += w * u.y;
      }
    }
    sm[nl * 132 + lane * 2]     = ax;
    sm[nl * 132 + lane * 2 + 1] = ay;
  }
  __syncthreads();
  int tx = tid & 63, ty = tid >> 6;
  float4 a0 = {0,0,0,0}, a1 = {0,0,0,0}, a2 = {0,0,0,0}, a3 = {0,0,0,0};
  #pragma unroll 4
  for (int k = 0; k < FIN; ++k) {
    float4 w = *(const float4*)(W1 + (size_t)k * HID + tx * 4);
    float x0 = sm[(ty * 4 + 0) * 132 + k];
    float x1 = sm[(ty * 4 + 1) * 132 + k];
    float x2 = sm[(ty * 4 + 2) * 132 + k];
    float x3 = sm[(ty * 4 + 3) * 132 + k];
    a0.x += x0 * w.x; a0.y += x0 * w.y; a0.z += x0 * w.z; a0.w += x0 * w.w;
    a1.x += x1 * w.x; a1.y += x1 * w.y; a1.z += x1 * w.z; a1.w += x1 * w.w;
    a2.x += x2 * w.x; a2.y += x2 * w.y; a2.z += x2 * w.z; a2.w += x2 * w.w;
    a3.x += x3 * w.x; a3.y += x3 * w.y; a3.z += x3 * w.z; a3.w += x3 * w.w;
  }
  __syncthreads();
  float4 bv = *(const float4*)(b1 + tx * 4);
  {
    float4 hs;
    hs.x = fmaxf(a0.x + bv.x, 0.f); hs.y = fmaxf(a0.y + bv.y, 0.f);
    hs.z = fmaxf(a0.z + bv.z, 0.f); hs.w = fmaxf(a0.w + bv.w, 0.f);
    *(float4*)(sm + (ty * 4 + 0) * 260 + tx * 4) = hs;
    hs.x = fmaxf(a1.x + bv.x, 0.f); hs.y = fmaxf(a1.y + bv.y, 0.f);
    hs.z = fmaxf(a1.z + bv.z, 0.f); hs.w = fmaxf(a1.w + bv.w, 0.f);
    *(float4*)(sm + (ty * 4 + 1) * 260 + tx * 4) = hs;
    hs.x = fmaxf(a2.x + bv.x, 0.f); hs.y = fmaxf(a2.y + bv.y, 0.f);
    hs.z = fmaxf(a2.z + bv.z, 0.f); hs.w = fmaxf(a2.w + bv.w, 0.f);
    *(float4*)(sm + (ty * 4 + 2) * 260 + tx * 4) = hs;
    hs.x = fmaxf(a3.x + bv.x, 0.f); hs.y = fmaxf(a3.y + bv.y, 0.f);
    hs.z = fmaxf(a3.z + bv.z, 0.f); hs.w = fmaxf(a3.w + bv.w, 0.f);
    *(float4*)(sm + (ty * 4 + 3) * 260 + tx * 4) = hs;
  }
  __syncthreads();
  int nn = tid >> 4, c0 = tid & 15;
  float acc0 = 0.f, acc1 = 0.f, acc2 = 0.f;
  #pragma unroll 4
  for (int k4 = 0; k4 < HID / 4; ++k4) {
    float4 hv = *(const float4*)(sm + nn * 260 + k4 * 4);
    float4 wa = *(const float4*)(w2s + k4 * 160 + c0 * 4);
    float4 wb = *(const float4*)(w2s + k4 * 160 + (c0 + 16) * 4);
    acc0 += hv.x * wa.x + hv.y * wa.y + hv.z * wa.z + hv.w * wa.w;
    acc1 += hv.x * wb.x + hv.y * wb.y + hv.z * wb.z + hv.w * wb.w;
    if (c0 < 8) {
      float4 wc = *(const float4*)(w2s + k4 * 160 + (c0 + 32) * 4);
      acc2 += hv.x * wc.x + hv.y * wc.y + hv.z * wc.z + hv.w * wc.w;
    }
  }
  ll nodeg = (ll)n0 + nn;
  if (nodeg < n) {
    float* o = xw2 + nodeg * FOUT;
    o[c0] = acc0;
    o[c0 + 16] = acc1;
    if (c0 < 8) o[c0 + 32] = acc2;
  }
}

// ---------------------------------------------------------------------------
// Layer 2 aggregation + bias + log_softmax. Wave per node, lane = class.
// 4x edge unroll -> 4 gather rows in flight per wave.
// ---------------------------------------------------------------------------
__global__ __launch_bounds__(256) void k_layer2(
    const float* __restrict__ xw2, const int* __restrict__ csr,
    const int* __restrict__ row_off, const float* __restrict__ dis,
    const float* __restrict__ b2, float* __restrict__ out, int n)
{
  int node = blockIdx.x * 4 + (threadIdx.x >> 6);
  int c = threadIdx.x & 63;
  if (node >= n) return;
  float di = dis[node];
  float acc0 = 0.f, acc1 = 0.f, acc2 = 0.f, acc3 = 0.f;
  if (c < FOUT) acc0 = di * di * xw2[(size_t)node * FOUT + c];
  int e0 = row_off[node], e1 = row_off[node + 1];
  int e = e0;
  for (; e + 4 <= e1; e += 4) {
    int s0 = csr[e], s1 = csr[e + 1], s2 = csr[e + 2], s3 = csr[e + 3];
    float w0 = di * dis[s0], w1 = di * dis[s1];
    float w2 = di * dis[s2], w3 = di * dis[s3];
    if (c < FOUT) {
      acc0 += w0 * xw2[(size_t)s0 * FOUT + c];
      acc1 += w1 * xw2[(size_t)s1 * FOUT + c];
      acc2 += w2 * xw2[(size_t)s2 * FOUT + c];
      acc3 += w3 * xw2[(size_t)s3 * FOUT + c];
    }
  }
  for (; e < e1; ++e) {
    int s = csr[e];
    float w = di * dis[s];
    if (c < FOUT) acc0 += w * xw2[(size_t)s * FOUT + c];
  }
  float acc = (acc0 + acc1) + (acc2 + acc3);
  float logit = (c < FOUT) ? (acc + b2[c]) : -INFINITY;
  float m = logit;
  #pragma unroll
  for (int off = 32; off > 0; off >>= 1) m = fmaxf(m, __shfl_xor(m, off));
  float ex = (c < FOUT) ? expf(logit - m) : 0.f;
  float sum = ex;
  #pragma unroll
  for (int off = 32; off > 0; off >>= 1) sum += __shfl_xor(sum, off);
  if (c < FOUT) out[(size_t)node * FOUT + c] = logit - m - logf(sum);
}

// ---------------------------------------------------------------------------
extern "C" void kernel_launch(void* const* d_in, const int* in_sizes, int n_in,
                              void* d_out, int out_size, void* d_ws, size_t ws_size,
                              hipStream_t stream) {
  const float* x  = (const float*)d_in[0];
  const void*  ei = d_in[1];
  const float* W1 = (const float*)d_in[2];
  const float* b1 = (const float*)d_in[3];
  const float* W2 = (const float*)d_in[4];
  const float* b2 = (const float*)d_in[5];
  float* out = (float*)d_out;

  int n = in_sizes[0] / FIN;        // 100000
  ll  E = (ll)in_sizes[1] / 2;      // 1600000
  int nb = (n + 4095) / 4096;

  char* ws = (char*)d_ws;
  size_t off = 0;
  auto carve = [&](size_t bytes) -> char* {
    char* p = ws + off;
    off = (off + bytes + 255) & ~(size_t)255;
    return p;
  };
  int*   flag    = (int*)carve(16);
  int*   row_off = (int*)carve((size_t)(n + 1) * 4);
  int*   cursor  = (int*)carve((size_t)n * 4);
  int*   csr     = (int*)carve((size_t)E * 4);
  int*   blksums = (int*)carve(64 * 4);
  float* dis     = (float*)carve((size_t)n * 4);
  float* xw2     = (float*)carve((size_t)n * FOUT * 4);
  float* h       = (float*)carve((size_t)n * HID * 4);  // 102.4 MB, split path only
  bool split = (off <= ws_size);
  (void)n_in; (void)out_size;

  int gn256 = (n + 255) / 256;
  int gE256 = (int)((E + 255) / 256);

  hipLaunchKernelGGL(k_detect, dim3(1), dim3(1), 0, stream, (const unsigned*)ei, flag);
  hipLaunchKernelGGL(k_zero,   dim3(gn256), dim3(256), 0, stream, cursor, n);
  hipLaunchKernelGGL(k_count,  dim3(gE256), dim3(256), 0, stream, ei, flag, cursor, E);
  hipLaunchKernelGGL(k_scan1,  dim3(nb), dim3(1024), 0, stream, cursor, row_off, blksums, n);
  hipLaunchKernelGGL(k_scan2,  dim3(1), dim3(1), 0, stream, blksums, nb);
  hipLaunchKernelGGL(k_scan3,  dim3((n + 1023) / 1024), dim3(1024), 0, stream,
                     row_off, cursor, blksums, n, nb);
  hipLaunchKernelGGL(k_dis,    dim3(gn256), dim3(256), 0, stream, row_off, dis, n);
  hipLaunchKernelGGL(k_fill,   dim3(gE256), dim3(256), 0, stream, ei, flag, cursor, csr, E);

  if (split) {
    hipLaunchKernelGGL(k_agg1,  dim3((n + 15) / 16), dim3(256), 0, stream,
                       x, csr, row_off, dis, W1, b1, h, n);
    hipLaunchKernelGGL(k_gemm2, dim3((n + 63) / 64), dim3(256), 0, stream,
                       h, W2, xw2, n);
  } else {
    hipLaunchKernelGGL(k_layer1, dim3((n + 15) / 16), dim3(256), 0, stream,
                       x, csr, row_off, dis, W1, b1, W2, xw2, n);
  }
  hipLaunchKernelGGL(k_layer2, dim3((n + 3) / 4), dim3(256), 0, stream,
                     xw2, csr, row_off, dis, b2, out, n);
}

// Round 3
// 530.360 us; speedup vs baseline: 1.9622x; 1.1025x over previous
//
#include <hip/hip_runtime.h>
#include <math.h>

typedef long long ll;
typedef unsigned int uint;

#define FIN 128
#define HID 256
#define FOUT 40
// xw2b rows are padded to 64 bf16 elements = 128 B (one L2 line per gather)

// ---------------------------------------------------------------------------
// bf16 helpers (manual, deterministic RNE)
// ---------------------------------------------------------------------------
__device__ __forceinline__ float bflo(uint u) { return __uint_as_float(u << 16); }
__device__ __forceinline__ float bfhi(uint u) { return __uint_as_float(u & 0xFFFF0000u); }
__device__ __forceinline__ float bfu(unsigned short u) { return __uint_as_float((uint)u << 16); }
__device__ __forceinline__ unsigned short f2bf(float f) {
  uint u = __float_as_uint(f);
  u += 0x7FFFu + ((u >> 16) & 1u);   // round-to-nearest-even
  return (unsigned short)(u >> 16);
}

// ---------------------------------------------------------------------------
// edge_index may arrive as int64 or int32. Detect on device: for int64 data
// the high words of values < 100000 are all zero.
// ---------------------------------------------------------------------------
__device__ __forceinline__ int edge_val(const void* ei, ll idx, int is64) {
  return is64 ? (int)((const ll*)ei)[idx] : ((const int*)ei)[idx];
}

__global__ void k_init(const unsigned* __restrict__ ei, int* __restrict__ flag,
                       int* __restrict__ cnt, int n) {
  int i = blockIdx.x * 256 + threadIdx.x;
  if (i == 0)
    flag[0] = (ei[1] == 0u && ei[3] == 0u && ei[5] == 0u && ei[7] == 0u) ? 1 : 0;
  if (i < n) cnt[i] = 0;
}

// x (f32) -> xb (bf16), 8 elems/thread
__global__ void k_xcast(const float* __restrict__ x, unsigned short* __restrict__ xb,
                        int total8) {
  int i = blockIdx.x * 256 + threadIdx.x;
  if (i >= total8) return;
  const float4* p = (const float4*)x + (size_t)i * 2;
  float4 a = p[0], b = p[1];
  uint4 o;
  o.x = (uint)f2bf(a.x) | ((uint)f2bf(a.y) << 16);
  o.y = (uint)f2bf(a.z) | ((uint)f2bf(a.w) << 16);
  o.z = (uint)f2bf(b.x) | ((uint)f2bf(b.y) << 16);
  o.w = (uint)f2bf(b.z) | ((uint)f2bf(b.w) << 16);
  *(uint4*)(xb + (size_t)i * 8) = o;
}

// degree count, 4 edges/thread with vector loads where alignment permits
__global__ void k_count(const void* __restrict__ ei, const int* __restrict__ flag,
                        int* __restrict__ cnt, ll E) {
  ll base = ((ll)blockIdx.x * 256 + threadIdx.x) * 4;
  if (base >= E) return;
  int is64 = flag[0];
  int m = (int)((E - base < 4) ? (E - base) : 4);
  int d[4];
  if (is64) {
    if (m == 4 && ((E + base) & 1) == 0) {
      longlong2 v0 = *(const longlong2*)((const ll*)ei + E + base);
      longlong2 v1 = *(const longlong2*)((const ll*)ei + E + base + 2);
      d[0] = (int)v0.x; d[1] = (int)v0.y; d[2] = (int)v1.x; d[3] = (int)v1.y;
    } else {
      for (int j = 0; j < m; ++j) d[j] = (int)((const ll*)ei)[E + base + j];
    }
  } else {
    if (m == 4 && ((E + base) & 3) == 0) {
      int4 v = *(const int4*)((const int*)ei + E + base);
      d[0] = v.x; d[1] = v.y; d[2] = v.z; d[3] = v.w;
    } else {
      for (int j = 0; j < m; ++j) d[j] = ((const int*)ei)[E + base + j];
    }
  }
  for (int j = 0; j < m; ++j) atomicAdd(&cnt[d[j]], 1);
}

// -------------------- exclusive prefix scan over counts --------------------
__global__ __launch_bounds__(1024) void k_scan1(const int* __restrict__ cnt,
                                                int* __restrict__ row_off,
                                                int* __restrict__ blksums, int n) {
  __shared__ int sm[1024];
  int t = threadIdx.x;
  int base = blockIdx.x * 4096 + t * 4;
  int v0 = (base + 0 < n) ? cnt[base + 0] : 0;
  int v1 = (base + 1 < n) ? cnt[base + 1] : 0;
  int v2 = (base + 2 < n) ? cnt[base + 2] : 0;
  int v3 = (base + 3 < n) ? cnt[base + 3] : 0;
  int s = v0 + v1 + v2 + v3;
  sm[t] = s;
  __syncthreads();
  for (int off = 1; off < 1024; off <<= 1) {
    int u = (t >= off) ? sm[t - off] : 0;
    __syncthreads();
    sm[t] += u;
    __syncthreads();
  }
  int excl = sm[t] - s;
  if (base + 0 < n) row_off[base + 0] = excl;
  if (base + 1 < n) row_off[base + 1] = excl + v0;
  if (base + 2 < n) row_off[base + 2] = excl + v0 + v1;
  if (base + 3 < n) row_off[base + 3] = excl + v0 + v1 + v2;
  if (t == 1023) blksums[blockIdx.x] = sm[1023];
}

__global__ void k_scan2(int* __restrict__ blksums, int nb) {
  if (threadIdx.x == 0 && blockIdx.x == 0) {
    int acc = 0;
    for (int i = 0; i < nb; ++i) { int v = blksums[i]; blksums[i] = acc; acc += v; }
    blksums[nb] = acc;  // total == E
  }
}

// scan finalize + dis = rsqrt(deg+1). cursor[] still holds raw counts here.
__global__ void k_scan3(int* __restrict__ row_off, int* __restrict__ cursor,
                        const int* __restrict__ blksums, float* __restrict__ dis,
                        int n, int nb) {
  int i = blockIdx.x * 1024 + threadIdx.x;
  if (i < n) {
    int c = cursor[i];
    int v = row_off[i] + blksums[i >> 12];
    row_off[i] = v;
    cursor[i] = v;
    dis[i] = rsqrtf((float)c + 1.0f);
  }
  if (i == 0) row_off[n] = blksums[nb];
}

// CSR fill; entry = {src, dis[src]} so consumers have no dependent dis load
__global__ void k_fill(const void* __restrict__ ei, const int* __restrict__ flag,
                       const float* __restrict__ dis, int* __restrict__ cursor,
                       int2* __restrict__ csr2, ll E) {
  ll e = (ll)blockIdx.x * 256 + threadIdx.x;
  if (e < E) {
    int is64 = flag[0];
    int src = edge_val(ei, e, is64);
    int dst = edge_val(ei, E + e, is64);
    float wsrc = dis[src];
    int pos = atomicAdd(&cursor[dst], 1);
    csr2[pos] = make_int2(src, __float_as_int(wsrc));
  }
}

__device__ __forceinline__ void acc8(float* a, uint4 r, float w) {
  a[0] += w * bflo(r.x); a[1] += w * bfhi(r.x);
  a[2] += w * bflo(r.y); a[3] += w * bfhi(r.y);
  a[4] += w * bflo(r.z); a[5] += w * bfhi(r.z);
  a[6] += w * bflo(r.w); a[7] += w * bfhi(r.w);
}

// ---------------------------------------------------------------------------
// k_agg1: per 16-node tile:
//   P1: quarter-wave (16 lanes x 16B bf16) per node, 4 nodes/wave,
//       4x edge unroll -> 16 rows in flight per wave. agg(f32) -> LDS [16][132]
//   P2: GEMM agg[16x128] @ W1[128x256] (+b1, ReLU) -> h (bf16) global
// ---------------------------------------------------------------------------
__global__ __launch_bounds__(256) void k_agg1(
    const unsigned short* __restrict__ xb, const int2* __restrict__ csr2,
    const int* __restrict__ row_off, const float* __restrict__ dis,
    const float* __restrict__ W1, const float* __restrict__ b1,
    unsigned short* __restrict__ h, int n)
{
  __shared__ __align__(16) float xs[16 * 132];
  int tid = threadIdx.x;
  int n0 = blockIdx.x * 16;
  int wv = tid >> 6, lane = tid & 63, qq = lane >> 4, l16 = lane & 15;
  int nl = wv * 4 + qq;
  int node = n0 + nl;

  float a[8] = {0, 0, 0, 0, 0, 0, 0, 0};
  if (node < n) {
    float di = dis[node];
    uint4 v = *((const uint4*)(xb + (size_t)node * FIN) + l16);
    acc8(a, v, di * di);
    int e0 = row_off[node], e1 = row_off[node + 1];
    int e = e0;
    for (; e + 4 <= e1; e += 4) {
      int2 c0 = csr2[e], c1 = csr2[e + 1], c2 = csr2[e + 2], c3 = csr2[e + 3];
      uint4 r0 = *((const uint4*)(xb + (size_t)c0.x * FIN) + l16);
      uint4 r1 = *((const uint4*)(xb + (size_t)c1.x * FIN) + l16);
      uint4 r2 = *((const uint4*)(xb + (size_t)c2.x * FIN) + l16);
      uint4 r3 = *((const uint4*)(xb + (size_t)c3.x * FIN) + l16);
      acc8(a, r0, di * __int_as_float(c0.y));
      acc8(a, r1, di * __int_as_float(c1.y));
      acc8(a, r2, di * __int_as_float(c2.y));
      acc8(a, r3, di * __int_as_float(c3.y));
    }
    for (; e < e1; ++e) {
      int2 c0 = csr2[e];
      uint4 r0 = *((const uint4*)(xb + (size_t)c0.x * FIN) + l16);
      acc8(a, r0, di * __int_as_float(c0.y));
    }
  }
  *(float4*)(xs + nl * 132 + l16 * 8)     = make_float4(a[0], a[1], a[2], a[3]);
  *(float4*)(xs + nl * 132 + l16 * 8 + 4) = make_float4(a[4], a[5], a[6], a[7]);
  __syncthreads();

  // P2: 4 nodes x 4 cols per thread; W1 rows streamed (L2-resident, 131KB)
  int tx = tid & 63, ty = tid >> 6;
  float4 acc[4] = {{0,0,0,0},{0,0,0,0},{0,0,0,0},{0,0,0,0}};
  #pragma unroll 4
  for (int k = 0; k < FIN; ++k) {
    float4 w = *(const float4*)(W1 + (size_t)k * HID + tx * 4);
    #pragma unroll
    for (int j = 0; j < 4; ++j) {
      float xv = xs[(ty * 4 + j) * 132 + k];
      acc[j].x += xv * w.x; acc[j].y += xv * w.y;
      acc[j].z += xv * w.z; acc[j].w += xv * w.w;
    }
  }
  float4 bv = *(const float4*)(b1 + tx * 4);
  #pragma unroll
  for (int j = 0; j < 4; ++j) {
    int nodeg = n0 + ty * 4 + j;
    if (nodeg < n) {
      ushort4 ho;
      ho.x = f2bf(fmaxf(acc[j].x + bv.x, 0.f));
      ho.y = f2bf(fmaxf(acc[j].y + bv.y, 0.f));
      ho.z = f2bf(fmaxf(acc[j].z + bv.z, 0.f));
      ho.w = f2bf(fmaxf(acc[j].w + bv.w, 0.f));
      *(ushort4*)(h + (size_t)nodeg * HID + tx * 4) = ho;
    }
  }
}

// ---------------------------------------------------------------------------
// k_gemm2: h[n x 256](bf16) @ W2[256 x 40] -> xw2b[n x 64pad](bf16).
// W2 staged once per block (40KB LDS); 4 subtiles of 16 nodes staged to LDS.
// ---------------------------------------------------------------------------
__global__ __launch_bounds__(256) void k_gemm2(
    const unsigned short* __restrict__ h, const float* __restrict__ W2,
    unsigned short* __restrict__ xw2b, int n)
{
  __shared__ __align__(16) float w2s[64 * 160];   // 40KB, [k/4][col][k%4]
  __shared__ __align__(16) float hs[16 * 260];    // 16.25KB
  int tid = threadIdx.x;
  for (int i = tid; i < HID * FOUT; i += 256) {
    int k = i / FOUT;
    int c = i - k * FOUT;
    w2s[(k >> 2) * 160 + c * 4 + (k & 3)] = W2[i];
  }
  int n0 = blockIdx.x * 64;
  int nn = tid >> 4, c0 = tid & 15;
  for (int sub = 0; sub < 4; ++sub) {
    int base = n0 + sub * 16;
    __syncthreads();  // protect hs from previous subtile's readers (and w2s on sub=0)
    for (int i = tid; i < 512; i += 256) {   // 16 rows x 32 chunks of 8 bf16
      int r = i >> 5, cc = i & 31;
      uint4 v = {0, 0, 0, 0};
      if (base + r < n) v = *((const uint4*)(h + (size_t)(base + r) * HID) + cc);
      float* dp = hs + r * 260 + cc * 8;
      dp[0] = bflo(v.x); dp[1] = bfhi(v.x); dp[2] = bflo(v.y); dp[3] = bfhi(v.y);
      dp[4] = bflo(v.z); dp[5] = bfhi(v.z); dp[6] = bflo(v.w); dp[7] = bfhi(v.w);
    }
    __syncthreads();
    float acc0 = 0.f, acc1 = 0.f, acc2 = 0.f;
    #pragma unroll 4
    for (int k4 = 0; k4 < HID / 4; ++k4) {
      float4 hv = *(const float4*)(hs + nn * 260 + k4 * 4);
      float4 wa = *(const float4*)(w2s + k4 * 160 + c0 * 4);
      float4 wb = *(const float4*)(w2s + k4 * 160 + (c0 + 16) * 4);
      acc0 += hv.x * wa.x + hv.y * wa.y + hv.z * wa.z + hv.w * wa.w;
      acc1 += hv.x * wb.x + hv.y * wb.y + hv.z * wb.z + hv.w * wb.w;
      if (c0 < 8) {
        float4 wc = *(const float4*)(w2s + k4 * 160 + (c0 + 32) * 4);
        acc2 += hv.x * wc.x + hv.y * wc.y + hv.z * wc.z + hv.w * wc.w;
      }
    }
    ll g = (ll)base + nn;
    if (g < n) {
      unsigned short* o = xw2b + ((size_t)g << 6);
      o[c0] = f2bf(acc0);
      o[c0 + 16] = f2bf(acc1);
      if (c0 < 8) o[c0 + 32] = f2bf(acc2);
    }
  }
}

// ---------------------------------------------------------------------------
// Layer 2 aggregation + bias + log_softmax. Wave per node, lane = class.
// bf16 gather rows (128B-aligned), 4x edge unroll, weights from csr2.
// ---------------------------------------------------------------------------
__global__ __launch_bounds__(256) void k_layer2(
    const unsigned short* __restrict__ xw2b, const int2* __restrict__ csr2,
    const int* __restrict__ row_off, const float* __restrict__ dis,
    const float* __restrict__ b2, float* __restrict__ out, int n)
{
  int node = blockIdx.x * 4 + (threadIdx.x >> 6);
  int c = threadIdx.x & 63;
  if (node >= n) return;
  float di = dis[node];
  bool act = (c < FOUT);
  float acc0 = 0.f, acc1 = 0.f, acc2 = 0.f, acc3 = 0.f;
  if (act) acc0 = di * di * bfu(xw2b[((size_t)node << 6) + c]);
  int e0 = row_off[node], e1 = row_off[node + 1];
  int e = e0;
  for (; e + 4 <= e1; e += 4) {
    int2 c0 = csr2[e], c1 = csr2[e + 1], c2 = csr2[e + 2], c3 = csr2[e + 3];
    if (act) {
      acc0 += di * __int_as_float(c0.y) * bfu(xw2b[((size_t)c0.x << 6) + c]);
      acc1 += di * __int_as_float(c1.y) * bfu(xw2b[((size_t)c1.x << 6) + c]);
      acc2 += di * __int_as_float(c2.y) * bfu(xw2b[((size_t)c2.x << 6) + c]);
      acc3 += di * __int_as_float(c3.y) * bfu(xw2b[((size_t)c3.x << 6) + c]);
    }
  }
  for (; e < e1; ++e) {
    int2 c0 = csr2[e];
    if (act) acc0 += di * __int_as_float(c0.y) * bfu(xw2b[((size_t)c0.x << 6) + c]);
  }
  float acc = (acc0 + acc1) + (acc2 + acc3);
  float logit = act ? (acc + b2[c]) : -INFINITY;
  float m = logit;
  #pragma unroll
  for (int off = 32; off > 0; off >>= 1) m = fmaxf(m, __shfl_xor(m, off));
  float ex = act ? expf(logit - m) : 0.f;
  float sum = ex;
  #pragma unroll
  for (int off = 32; off > 0; off >>= 1) sum += __shfl_xor(sum, off);
  if (act) out[(size_t)node * FOUT + c] = logit - m - logf(sum);
}

// ---------------------------------------------------------------------------
extern "C" void kernel_launch(void* const* d_in, const int* in_sizes, int n_in,
                              void* d_out, int out_size, void* d_ws, size_t ws_size,
                              hipStream_t stream) {
  const float* x  = (const float*)d_in[0];
  const void*  ei = d_in[1];
  const float* W1 = (const float*)d_in[2];
  const float* b1 = (const float*)d_in[3];
  const float* W2 = (const float*)d_in[4];
  const float* b2 = (const float*)d_in[5];
  float* out = (float*)d_out;

  int n = in_sizes[0] / FIN;        // 100000
  ll  E = (ll)in_sizes[1] / 2;      // 1600000
  int nb = (n + 4095) / 4096;

  char* ws = (char*)d_ws;
  size_t off = 0;
  auto carve = [&](size_t bytes) -> char* {
    char* p = ws + off;
    off = (off + bytes + 255) & ~(size_t)255;
    return p;
  };
  int*   flag    = (int*)carve(16);
  int*   row_off = (int*)carve((size_t)(n + 1) * 4);
  int*   cursor  = (int*)carve((size_t)n * 4);
  int2*  csr2    = (int2*)carve((size_t)E * 8);            // 12.8 MB
  int*   blksums = (int*)carve(64 * 4);
  float* dis     = (float*)carve((size_t)n * 4);
  unsigned short* xb   = (unsigned short*)carve((size_t)n * FIN * 2);  // 25.6 MB
  unsigned short* h    = (unsigned short*)carve((size_t)n * HID * 2);  // 51.2 MB
  unsigned short* xw2b = (unsigned short*)carve((size_t)n * 64 * 2);   // 12.8 MB
  (void)n_in; (void)out_size; (void)ws_size;  // total ~104 MB, fits (R2 used ~127 MB)

  int gn256 = (n + 255) / 256;
  int gE256 = (int)((E + 255) / 256);
  int gE4   = (int)((E + 1023) / 1024);      // 4 edges/thread
  int gx8   = (n * FIN / 8 + 255) / 256;

  hipLaunchKernelGGL(k_init,  dim3(gn256), dim3(256), 0, stream,
                     (const unsigned*)ei, flag, cursor, n);
  hipLaunchKernelGGL(k_count, dim3(gE4), dim3(256), 0, stream, ei, flag, cursor, E);
  hipLaunchKernelGGL(k_scan1, dim3(nb), dim3(1024), 0, stream, cursor, row_off, blksums, n);
  hipLaunchKernelGGL(k_scan2, dim3(1), dim3(1), 0, stream, blksums, nb);
  hipLaunchKernelGGL(k_scan3, dim3((n + 1023) / 1024), dim3(1024), 0, stream,
                     row_off, cursor, blksums, dis, n, nb);
  hipLaunchKernelGGL(k_fill,  dim3(gE256), dim3(256), 0, stream,
                     ei, flag, dis, cursor, csr2, E);
  hipLaunchKernelGGL(k_xcast, dim3(gx8), dim3(256), 0, stream, x, xb, n * FIN / 8);
  hipLaunchKernelGGL(k_agg1,  dim3((n + 15) / 16), dim3(256), 0, stream,
                     xb, csr2, row_off, dis, W1, b1, h, n);
  hipLaunchKernelGGL(k_gemm2, dim3((n + 63) / 64), dim3(256), 0, stream,
                     h, W2, xw2b, n);
  hipLaunchKernelGGL(k_layer2, dim3((n + 3) / 4), dim3(256), 0, stream,
                     xw2b, csr2, row_off, dis, b2, out, n);
}

// Round 4
// 323.488 us; speedup vs baseline: 3.2170x; 1.6395x over previous
//
#include <hip/hip_runtime.h>
#include <math.h>

typedef long long ll;
typedef unsigned int uint;
typedef __attribute__((ext_vector_type(8))) short bf16x8;
typedef __attribute__((ext_vector_type(4))) float f32x4;

#define FIN 128
#define HID 256
#define FOUT 40
// xw2b rows padded to 64 bf16 (128 B = one L2 line per layer-2 gather)

// ---------------------------------------------------------------------------
// bf16 helpers (manual, deterministic RNE)
// ---------------------------------------------------------------------------
__device__ __forceinline__ float bflo(uint u) { return __uint_as_float(u << 16); }
__device__ __forceinline__ float bfhi(uint u) { return __uint_as_float(u & 0xFFFF0000u); }
__device__ __forceinline__ unsigned short f2bf(float f) {
  uint u = __float_as_uint(f);
  u += 0x7FFFu + ((u >> 16) & 1u);   // round-to-nearest-even
  return (unsigned short)(u >> 16);
}

// ---------------------------------------------------------------------------
// edge_index may arrive as int64 or int32. Detect on device: for int64 data
// the high words of values < 100000 are all zero.
// ---------------------------------------------------------------------------
__device__ __forceinline__ int edge_val(const void* ei, ll idx, int is64) {
  return is64 ? (int)((const ll*)ei)[idx] : ((const int*)ei)[idx];
}

// k_init: flag detect + zero degree counters + pack W1,W2 to bf16 in MFMA
// B-fragment order: wp[((s*C + c)*4 + g)*8 + j] = W[s*32 + g*8 + j][c]
// so lane l (col c = base + (l&15), g = l>>4) reads 8 consecutive bf16 = 16B.
__global__ void k_init(const unsigned* __restrict__ ei, int* __restrict__ flag,
                       int* __restrict__ cnt,
                       const float* __restrict__ W1, const float* __restrict__ W2,
                       unsigned short* __restrict__ w1p,
                       unsigned short* __restrict__ w2p, int n) {
  int i = blockIdx.x * 256 + threadIdx.x;
  if (i == 0)
    flag[0] = (ei[1] == 0u && ei[3] == 0u && ei[5] == 0u && ei[7] == 0u) ? 1 : 0;
  if (i < n) cnt[i] = 0;
  if (i < 32768) {                     // W1p: 4 ksteps x 256 cols x 4 g x 8 j
    int j = i & 7, g = (i >> 3) & 3, c = (i >> 5) & 255, s = i >> 13;
    int k = s * 32 + g * 8 + j;
    w1p[i] = f2bf(W1[(size_t)k * HID + c]);
  } else if (i < 32768 + 12288) {      // W2p: 8 ksteps x 48 cols x 4 g x 8 j
    int i2 = i - 32768;
    int j = i2 & 7, g = (i2 >> 3) & 3, q = i2 >> 5;
    int c = q % 48, s = q / 48;
    int k = s * 32 + g * 8 + j;
    w2p[i2] = (c < FOUT) ? f2bf(W2[(size_t)k * FOUT + c]) : (unsigned short)0;
  }
}

// x (f32) -> xb (bf16), 8 elems/thread
__global__ void k_xcast(const float* __restrict__ x, unsigned short* __restrict__ xb,
                        int total8) {
  int i = blockIdx.x * 256 + threadIdx.x;
  if (i >= total8) return;
  const float4* p = (const float4*)x + (size_t)i * 2;
  float4 a = p[0], b = p[1];
  uint4 o;
  o.x = (uint)f2bf(a.x) | ((uint)f2bf(a.y) << 16);
  o.y = (uint)f2bf(a.z) | ((uint)f2bf(a.w) << 16);
  o.z = (uint)f2bf(b.x) | ((uint)f2bf(b.y) << 16);
  o.w = (uint)f2bf(b.z) | ((uint)f2bf(b.w) << 16);
  *(uint4*)(xb + (size_t)i * 8) = o;
}

// degree count, 4 edges/thread
__global__ void k_count(const void* __restrict__ ei, const int* __restrict__ flag,
                        int* __restrict__ cnt, ll E) {
  ll base = ((ll)blockIdx.x * 256 + threadIdx.x) * 4;
  if (base >= E) return;
  int is64 = flag[0];
  int m = (int)((E - base < 4) ? (E - base) : 4);
  int d[4];
  if (is64) {
    if (m == 4 && ((E + base) & 1) == 0) {
      longlong2 v0 = *(const longlong2*)((const ll*)ei + E + base);
      longlong2 v1 = *(const longlong2*)((const ll*)ei + E + base + 2);
      d[0] = (int)v0.x; d[1] = (int)v0.y; d[2] = (int)v1.x; d[3] = (int)v1.y;
    } else {
      for (int j = 0; j < m; ++j) d[j] = (int)((const ll*)ei)[E + base + j];
    }
  } else {
    if (m == 4 && ((E + base) & 3) == 0) {
      int4 v = *(const int4*)((const int*)ei + E + base);
      d[0] = v.x; d[1] = v.y; d[2] = v.z; d[3] = v.w;
    } else {
      for (int j = 0; j < m; ++j) d[j] = ((const int*)ei)[E + base + j];
    }
  }
  for (int j = 0; j < m; ++j) atomicAdd(&cnt[d[j]], 1);
}

// -------------------- exclusive prefix scan over counts --------------------
__global__ __launch_bounds__(1024) void k_scan1(const int* __restrict__ cnt,
                                                int* __restrict__ row_off,
                                                int* __restrict__ blksums, int n) {
  __shared__ int sm[1024];
  int t = threadIdx.x;
  int base = blockIdx.x * 4096 + t * 4;
  int v0 = (base + 0 < n) ? cnt[base + 0] : 0;
  int v1 = (base + 1 < n) ? cnt[base + 1] : 0;
  int v2 = (base + 2 < n) ? cnt[base + 2] : 0;
  int v3 = (base + 3 < n) ? cnt[base + 3] : 0;
  int s = v0 + v1 + v2 + v3;
  sm[t] = s;
  __syncthreads();
  for (int off = 1; off < 1024; off <<= 1) {
    int u = (t >= off) ? sm[t - off] : 0;
    __syncthreads();
    sm[t] += u;
    __syncthreads();
  }
  int excl = sm[t] - s;
  if (base + 0 < n) row_off[base + 0] = excl;
  if (base + 1 < n) row_off[base + 1] = excl + v0;
  if (base + 2 < n) row_off[base + 2] = excl + v0 + v1;
  if (base + 3 < n) row_off[base + 3] = excl + v0 + v1 + v2;
  if (t == 1023) blksums[blockIdx.x] = sm[1023];
}

__global__ void k_scan2(int* __restrict__ blksums, int nb) {
  if (threadIdx.x == 0 && blockIdx.x == 0) {
    int acc = 0;
    for (int i = 0; i < nb; ++i) { int v = blksums[i]; blksums[i] = acc; acc += v; }
    blksums[nb] = acc;  // total == E
  }
}

// scan finalize + dis = rsqrt(deg+1). cursor[] still holds raw counts here.
__global__ void k_scan3(int* __restrict__ row_off, int* __restrict__ cursor,
                        const int* __restrict__ blksums, float* __restrict__ dis,
                        int n, int nb) {
  int i = blockIdx.x * 1024 + threadIdx.x;
  if (i < n) {
    int c = cursor[i];
    int v = row_off[i] + blksums[i >> 12];
    row_off[i] = v;
    cursor[i] = v;
    dis[i] = rsqrtf((float)c + 1.0f);
  }
  if (i == 0) row_off[n] = blksums[nb];
}

// CSR fill; entry = {src, dis[src]} so consumers have no dependent dis load
__global__ void k_fill(const void* __restrict__ ei, const int* __restrict__ flag,
                       const float* __restrict__ dis, int* __restrict__ cursor,
                       int2* __restrict__ csr2, ll E) {
  ll e = (ll)blockIdx.x * 256 + threadIdx.x;
  if (e < E) {
    int is64 = flag[0];
    int src = edge_val(ei, e, is64);
    int dst = edge_val(ei, E + e, is64);
    float wsrc = dis[src];
    int pos = atomicAdd(&cursor[dst], 1);
    csr2[pos] = make_int2(src, __float_as_int(wsrc));
  }
}

__device__ __forceinline__ void acc8(float* a, uint4 r, float w) {
  a[0] += w * bflo(r.x); a[1] += w * bfhi(r.x);
  a[2] += w * bflo(r.y); a[3] += w * bfhi(r.y);
  a[4] += w * bflo(r.z); a[5] += w * bfhi(r.z);
  a[6] += w * bflo(r.w); a[7] += w * bfhi(r.w);
}

// ---------------------------------------------------------------------------
// k_fused1: per 16-node tile (256 threads = 4 waves):
//   P1 gather: quarter-wave per node, 4x edge unroll (16 rows in flight);
//      agg(f32 regs) -> bf16 -> LDS xsb[16][136]  (A-fragment layout)
//   P2 MFMA GEMM1: agg[16x128] @ W1[128x256]; wave w owns cols w*64..w*64+63
//      (4 col-tiles x 4 ksteps = 16 mfma_16x16x32_bf16); +b1, ReLU ->
//      LDS hsb[16][264] bf16
//   P3 MFMA GEMM2: h[16x256] @ W2[256x48pad]; waves 0..2 own one 16-col tile
//      (8 ksteps); write xw2b (cols < 40)
// LDS 12.8KB, B-fragments streamed from L2 (w1p/w2p pre-packed).
// ---------------------------------------------------------------------------
__global__ __launch_bounds__(256) void k_fused1(
    const unsigned short* __restrict__ xb, const int2* __restrict__ csr2,
    const int* __restrict__ row_off, const float* __restrict__ dis,
    const unsigned short* __restrict__ w1p, const float* __restrict__ b1,
    const unsigned short* __restrict__ w2p, unsigned short* __restrict__ xw2b,
    int n)
{
  __shared__ __align__(16) unsigned short xsb[16 * 136];  // 4.25KB, stride 272B (2-way)
  __shared__ __align__(16) unsigned short hsb[16 * 264];  // 8.25KB, stride 528B (2-way)

  int tid = threadIdx.x;
  int n0 = blockIdx.x * 16;
  int wv = tid >> 6, lane = tid & 63, qq = lane >> 4, l16 = lane & 15;
  int nl = wv * 4 + qq;
  int node = n0 + nl;

  // ---- P1: gather-aggregate ----
  float a[8] = {0, 0, 0, 0, 0, 0, 0, 0};
  if (node < n) {
    float di = dis[node];
    uint4 v = *((const uint4*)(xb + (size_t)node * FIN) + l16);
    acc8(a, v, di * di);
    int e0 = row_off[node], e1 = row_off[node + 1];
    int e = e0;
    for (; e + 4 <= e1; e += 4) {
      int2 c0 = csr2[e], c1 = csr2[e + 1], c2 = csr2[e + 2], c3 = csr2[e + 3];
      uint4 r0 = *((const uint4*)(xb + (size_t)c0.x * FIN) + l16);
      uint4 r1 = *((const uint4*)(xb + (size_t)c1.x * FIN) + l16);
      uint4 r2 = *((const uint4*)(xb + (size_t)c2.x * FIN) + l16);
      uint4 r3 = *((const uint4*)(xb + (size_t)c3.x * FIN) + l16);
      acc8(a, r0, di * __int_as_float(c0.y));
      acc8(a, r1, di * __int_as_float(c1.y));
      acc8(a, r2, di * __int_as_float(c2.y));
      acc8(a, r3, di * __int_as_float(c3.y));
    }
    for (; e < e1; ++e) {
      int2 c0 = csr2[e];
      uint4 r0 = *((const uint4*)(xb + (size_t)c0.x * FIN) + l16);
      acc8(a, r0, di * __int_as_float(c0.y));
    }
  }
  {
    uint4 pk;
    pk.x = (uint)f2bf(a[0]) | ((uint)f2bf(a[1]) << 16);
    pk.y = (uint)f2bf(a[2]) | ((uint)f2bf(a[3]) << 16);
    pk.z = (uint)f2bf(a[4]) | ((uint)f2bf(a[5]) << 16);
    pk.w = (uint)f2bf(a[6]) | ((uint)f2bf(a[7]) << 16);
    *(uint4*)(xsb + nl * 136 + l16 * 8) = pk;   // row nl, k = l16*8..+7
  }
  __syncthreads();

  // ---- P2: MFMA GEMM1 (agg @ W1) ----
  int mrow = lane & 15, g = lane >> 4;
  f32x4 acc1[4] = {{0,0,0,0},{0,0,0,0},{0,0,0,0},{0,0,0,0}};
  #pragma unroll
  for (int s = 0; s < 4; ++s) {
    bf16x8 av = *(const bf16x8*)(xsb + mrow * 136 + s * 32 + g * 8);
    #pragma unroll
    for (int t = 0; t < 4; ++t) {
      int c = wv * 64 + t * 16 + mrow;
      bf16x8 bv = *(const bf16x8*)(w1p + (((size_t)(s * 256 + c) * 4 + g) << 3));
      acc1[t] = __builtin_amdgcn_mfma_f32_16x16x32_bf16(av, bv, acc1[t], 0, 0, 0);
    }
  }
  // epilogue: +b1, ReLU -> hsb (D frag: row=(g*4+r), col=c)
  #pragma unroll
  for (int t = 0; t < 4; ++t) {
    int c = wv * 64 + t * 16 + mrow;
    float bb = b1[c];
    #pragma unroll
    for (int r = 0; r < 4; ++r) {
      float v = fmaxf(acc1[t][r] + bb, 0.f);
      hsb[(g * 4 + r) * 264 + c] = f2bf(v);
    }
  }
  __syncthreads();

  // ---- P3: MFMA GEMM2 (h @ W2), waves 0..2 own col tiles 0..2 ----
  if (wv < 3) {
    f32x4 acc2 = {0, 0, 0, 0};
    int c2 = wv * 16 + mrow;
    #pragma unroll
    for (int s = 0; s < 8; ++s) {
      bf16x8 av = *(const bf16x8*)(hsb + mrow * 264 + s * 32 + g * 8);
      bf16x8 bv = *(const bf16x8*)(w2p + (((size_t)(s * 48 + c2) * 4 + g) << 3));
      acc2 = __builtin_amdgcn_mfma_f32_16x16x32_bf16(av, bv, acc2, 0, 0, 0);
    }
    if (c2 < FOUT) {
      #pragma unroll
      for (int r = 0; r < 4; ++r) {
        int nodeg = n0 + g * 4 + r;
        if (nodeg < n) xw2b[((size_t)nodeg << 6) + c2] = f2bf(acc2[r]);
      }
    }
  }
}

// ---------------------------------------------------------------------------
// Layer 2 aggregation + bias + log_softmax. Quarter-wave (16 lanes) per node,
// lane = 4 cols via uint2; 4 nodes/wave, 4x edge unroll -> 16 rows in flight.
// ---------------------------------------------------------------------------
__global__ __launch_bounds__(256) void k_layer2(
    const unsigned short* __restrict__ xw2b, const int2* __restrict__ csr2,
    const int* __restrict__ row_off, const float* __restrict__ dis,
    const float* __restrict__ b2, float* __restrict__ out, int n)
{
  int tid = threadIdx.x;
  int node = blockIdx.x * 16 + (tid >> 4);
  int l16 = tid & 15;
  if (node >= n) return;
  float di = dis[node];
  float a0 = 0.f, a1 = 0.f, a2 = 0.f, a3 = 0.f;
  {
    uint2 v = *((const uint2*)(xw2b + ((size_t)node << 6)) + l16);
    float w = di * di;
    a0 = w * bflo(v.x); a1 = w * bfhi(v.x);
    a2 = w * bflo(v.y); a3 = w * bfhi(v.y);
  }
  int e0 = row_off[node], e1 = row_off[node + 1];
  int e = e0;
  for (; e + 4 <= e1; e += 4) {
    int2 c0 = csr2[e], c1 = csr2[e + 1], c2 = csr2[e + 2], c3 = csr2[e + 3];
    uint2 r0 = *((const uint2*)(xw2b + ((size_t)c0.x << 6)) + l16);
    uint2 r1 = *((const uint2*)(xw2b + ((size_t)c1.x << 6)) + l16);
    uint2 r2 = *((const uint2*)(xw2b + ((size_t)c2.x << 6)) + l16);
    uint2 r3 = *((const uint2*)(xw2b + ((size_t)c3.x << 6)) + l16);
    float w0 = di * __int_as_float(c0.y), w1 = di * __int_as_float(c1.y);
    float w2 = di * __int_as_float(c2.y), w3 = di * __int_as_float(c3.y);
    a0 += w0 * bflo(r0.x); a1 += w0 * bfhi(r0.x); a2 += w0 * bflo(r0.y); a3 += w0 * bfhi(r0.y);
    a0 += w1 * bflo(r1.x); a1 += w1 * bfhi(r1.x); a2 += w1 * bflo(r1.y); a3 += w1 * bfhi(r1.y);
    a0 += w2 * bflo(r2.x); a1 += w2 * bfhi(r2.x); a2 += w2 * bflo(r2.y); a3 += w2 * bfhi(r2.y);
    a0 += w3 * bflo(r3.x); a1 += w3 * bfhi(r3.x); a2 += w3 * bflo(r3.y); a3 += w3 * bfhi(r3.y);
  }
  for (; e < e1; ++e) {
    int2 c0 = csr2[e];
    uint2 r0 = *((const uint2*)(xw2b + ((size_t)c0.x << 6)) + l16);
    float w0 = di * __int_as_float(c0.y);
    a0 += w0 * bflo(r0.x); a1 += w0 * bfhi(r0.x);
    a2 += w0 * bflo(r0.y); a3 += w0 * bfhi(r0.y);
  }
  // bias + masked 16-lane softmax (cols 4*l16..+3 valid iff l16 < 10)
  bool act = (l16 < 10);
  float l0 = -INFINITY, l1 = -INFINITY, l2 = -INFINITY, l3 = -INFINITY;
  if (act) {
    float4 bv = *(const float4*)(b2 + l16 * 4);
    l0 = a0 + bv.x; l1 = a1 + bv.y; l2 = a2 + bv.z; l3 = a3 + bv.w;
  }
  float m = fmaxf(fmaxf(l0, l1), fmaxf(l2, l3));
  #pragma unroll
  for (int off = 8; off > 0; off >>= 1) m = fmaxf(m, __shfl_xor(m, off));
  float s = 0.f;
  if (act) s = expf(l0 - m) + expf(l1 - m) + expf(l2 - m) + expf(l3 - m);
  #pragma unroll
  for (int off = 8; off > 0; off >>= 1) s += __shfl_xor(s, off);
  if (act) {
    float ls = m + logf(s);
    float4 o = make_float4(l0 - ls, l1 - ls, l2 - ls, l3 - ls);
    *(float4*)(out + (size_t)node * FOUT + l16 * 4) = o;
  }
}

// ---------------------------------------------------------------------------
extern "C" void kernel_launch(void* const* d_in, const int* in_sizes, int n_in,
                              void* d_out, int out_size, void* d_ws, size_t ws_size,
                              hipStream_t stream) {
  const float* x  = (const float*)d_in[0];
  const void*  ei = d_in[1];
  const float* W1 = (const float*)d_in[2];
  const float* b1 = (const float*)d_in[3];
  const float* W2 = (const float*)d_in[4];
  const float* b2 = (const float*)d_in[5];
  float* out = (float*)d_out;

  int n = in_sizes[0] / FIN;        // 100000
  ll  E = (ll)in_sizes[1] / 2;      // 1600000
  int nb = (n + 4095) / 4096;

  char* ws = (char*)d_ws;
  size_t off = 0;
  auto carve = [&](size_t bytes) -> char* {
    char* p = ws + off;
    off = (off + bytes + 255) & ~(size_t)255;
    return p;
  };
  int*   flag    = (int*)carve(16);
  int*   row_off = (int*)carve((size_t)(n + 1) * 4);
  int*   cursor  = (int*)carve((size_t)n * 4);
  int2*  csr2    = (int2*)carve((size_t)E * 8);                        // 12.8 MB
  int*   blksums = (int*)carve(64 * 4);
  float* dis     = (float*)carve((size_t)n * 4);
  unsigned short* xb   = (unsigned short*)carve((size_t)n * FIN * 2);  // 25.6 MB
  unsigned short* w1p  = (unsigned short*)carve(32768 * 2);            // 64 KB
  unsigned short* w2p  = (unsigned short*)carve(12288 * 2);            // 24 KB
  unsigned short* xw2b = (unsigned short*)carve((size_t)n * 64 * 2);   // 12.8 MB
  (void)n_in; (void)out_size; (void)ws_size;  // total ~52 MB (R3's 104 MB fit)

  int gn256 = (n + 255) / 256;
  int gE256 = (int)((E + 255) / 256);
  int gE4   = (int)((E + 1023) / 1024);
  int gx8   = (n * FIN / 8 + 255) / 256;
  int gt16  = (n + 15) / 16;

  hipLaunchKernelGGL(k_init,  dim3(gn256), dim3(256), 0, stream,
                     (const unsigned*)ei, flag, cursor, W1, W2, w1p, w2p, n);
  hipLaunchKernelGGL(k_count, dim3(gE4), dim3(256), 0, stream, ei, flag, cursor, E);
  hipLaunchKernelGGL(k_scan1, dim3(nb), dim3(1024), 0, stream, cursor, row_off, blksums, n);
  hipLaunchKernelGGL(k_scan2, dim3(1), dim3(1), 0, stream, blksums, nb);
  hipLaunchKernelGGL(k_scan3, dim3((n + 1023) / 1024), dim3(1024), 0, stream,
                     row_off, cursor, blksums, dis, n, nb);
  hipLaunchKernelGGL(k_fill,  dim3(gE256), dim3(256), 0, stream,
                     ei, flag, dis, cursor, csr2, E);
  hipLaunchKernelGGL(k_xcast, dim3(gx8), dim3(256), 0, stream, x, xb, n * FIN / 8);
  hipLaunchKernelGGL(k_fused1, dim3(gt16), dim3(256), 0, stream,
                     xb, csr2, row_off, dis, w1p, b1, w2p, xw2b, n);
  hipLaunchKernelGGL(k_layer2, dim3(gt16), dim3(256), 0, stream,
                     xw2b, csr2, row_off, dis, b2, out, n);
}

// Round 5
// 313.937 us; speedup vs baseline: 3.3149x; 1.0304x over previous
//
#include <hip/hip_runtime.h>
#include <math.h>

typedef long long ll;
typedef unsigned int uint;
typedef __attribute__((ext_vector_type(8))) short bf16x8;
typedef __attribute__((ext_vector_type(4))) float f32x4;

#define FIN 128
#define HID 256
#define FOUT 40
#define NG 8            // dst-range groups (≈ XCD count)
// xw2b rows padded to 64 bf16 (128 B = one L2 line per layer-2 gather)

// ---------------------------------------------------------------------------
// bf16 helpers (manual, deterministic RNE)
// ---------------------------------------------------------------------------
__device__ __forceinline__ float bflo(uint u) { return __uint_as_float(u << 16); }
__device__ __forceinline__ float bfhi(uint u) { return __uint_as_float(u & 0xFFFF0000u); }
__device__ __forceinline__ unsigned short f2bf(float f) {
  uint u = __float_as_uint(f);
  u += 0x7FFFu + ((u >> 16) & 1u);   // round-to-nearest-even
  return (unsigned short)(u >> 16);
}

// int64 vs int32 edge_index: for int64 data the high words of values <100000
// are all zero. ei[1,3,5,7] are hi-words (int64) or src values (int32);
// random src values being all-zero has probability ~1e-20.
__device__ __forceinline__ int detect64(const uint* __restrict__ ei) {
  return (ei[1] == 0u && ei[3] == 0u && ei[5] == 0u && ei[7] == 0u) ? 1 : 0;
}

// ---------------------------------------------------------------------------
// k_init: zero degree counters + pack W1,W2 to bf16 B-fragment order +
// pack edge_index into int2 pairs {src,dst} (coalesced).
// B-frag order: wp[((s*C + c)*4 + g)*8 + j] = W[s*32 + g*8 + j][c]
// ---------------------------------------------------------------------------
__global__ __launch_bounds__(256) void k_init(
    const void* __restrict__ ei, int* __restrict__ cnt,
    const float* __restrict__ W1, const float* __restrict__ W2,
    unsigned short* __restrict__ w1p, unsigned short* __restrict__ w2p,
    int2* __restrict__ pairs, int n, ll E) {
  int i = blockIdx.x * 256 + threadIdx.x;
  int T = gridDim.x * 256;
  if (i < n) cnt[i] = 0;
  if (i < 32768) {                     // W1p: 4 ksteps x 256 cols x 4 g x 8 j
    int j = i & 7, g = (i >> 3) & 3, c = (i >> 5) & 255, s = i >> 13;
    int k = s * 32 + g * 8 + j;
    w1p[i] = f2bf(W1[(size_t)k * HID + c]);
  } else if (i < 32768 + 12288) {      // W2p: 8 ksteps x 48 cols x 4 g x 8 j
    int i2 = i - 32768;
    int j = i2 & 7, g = (i2 >> 3) & 3, q = i2 >> 5;
    int c = q % 48, s = q / 48;
    int k = s * 32 + g * 8 + j;
    w2p[i2] = (c < FOUT) ? f2bf(W2[(size_t)k * FOUT + c]) : (unsigned short)0;
  }
  // edge pack, 4 edges/thread/iter, grid-stride
  int is64 = detect64((const uint*)ei);
  for (ll base = (ll)i * 4; base < E; base += (ll)T * 4) {
    int m = (int)((E - base < 4) ? (E - base) : 4);
    int s[4], d[4];
    if (is64) {
      if (m == 4) {
        longlong2 a0 = *(const longlong2*)((const ll*)ei + base);
        longlong2 a1 = *(const longlong2*)((const ll*)ei + base + 2);
        longlong2 b0 = *(const longlong2*)((const ll*)ei + E + base);
        longlong2 b1 = *(const longlong2*)((const ll*)ei + E + base + 2);
        s[0]=(int)a0.x; s[1]=(int)a0.y; s[2]=(int)a1.x; s[3]=(int)a1.y;
        d[0]=(int)b0.x; d[1]=(int)b0.y; d[2]=(int)b1.x; d[3]=(int)b1.y;
      } else {
        for (int j = 0; j < m; ++j) { s[j]=(int)((const ll*)ei)[base+j]; d[j]=(int)((const ll*)ei)[E+base+j]; }
      }
    } else {
      if (m == 4) {
        int4 a = *(const int4*)((const int*)ei + base);
        int4 b = *(const int4*)((const int*)ei + E + base);
        s[0]=a.x; s[1]=a.y; s[2]=a.z; s[3]=a.w;
        d[0]=b.x; d[1]=b.y; d[2]=b.z; d[3]=b.w;
      } else {
        for (int j = 0; j < m; ++j) { s[j]=((const int*)ei)[base+j]; d[j]=((const int*)ei)[E+base+j]; }
      }
    }
    for (int j = 0; j < m; ++j) pairs[base + j] = make_int2(s[j], d[j]);
  }
}

// ---------------------------------------------------------------------------
// k_count: 8 block-groups; group g histograms only dst in [g*range,(g+1)*range)
// -> all atomics land in an L2-resident 50KB window per group.
// ---------------------------------------------------------------------------
__global__ __launch_bounds__(256) void k_count(
    const int2* __restrict__ pairs, int* __restrict__ cnt, ll E, int range, int n) {
  int g = blockIdx.x & (NG - 1);
  int lo = g * range;
  int hi = min(n, lo + range);
  ll tig = (ll)(blockIdx.x >> 3) * 256 + threadIdx.x;
  ll TIG = (ll)(gridDim.x >> 3) * 256;
  for (ll i = tig * 2; i < E; i += TIG * 2) {
    if (i + 1 < E) {
      int4 p = *(const int4*)(pairs + i);      // {s0,d0,s1,d1}
      if (p.y >= lo && p.y < hi) atomicAdd(&cnt[p.y], 1);
      if (p.w >= lo && p.w < hi) atomicAdd(&cnt[p.w], 1);
    } else {
      int2 p = pairs[i];
      if (p.y >= lo && p.y < hi) atomicAdd(&cnt[p.y], 1);
    }
  }
}

// -------------------- exclusive prefix scan over counts --------------------
__global__ __launch_bounds__(1024) void k_scan1(const int* __restrict__ cnt,
                                                int* __restrict__ row_off,
                                                int* __restrict__ blksums, int n) {
  __shared__ int sm[1024];
  int t = threadIdx.x;
  int base = blockIdx.x * 4096 + t * 4;
  int v0 = (base + 0 < n) ? cnt[base + 0] : 0;
  int v1 = (base + 1 < n) ? cnt[base + 1] : 0;
  int v2 = (base + 2 < n) ? cnt[base + 2] : 0;
  int v3 = (base + 3 < n) ? cnt[base + 3] : 0;
  int s = v0 + v1 + v2 + v3;
  sm[t] = s;
  __syncthreads();
  for (int off = 1; off < 1024; off <<= 1) {
    int u = (t >= off) ? sm[t - off] : 0;
    __syncthreads();
    sm[t] += u;
    __syncthreads();
  }
  int excl = sm[t] - s;
  if (base + 0 < n) row_off[base + 0] = excl;
  if (base + 1 < n) row_off[base + 1] = excl + v0;
  if (base + 2 < n) row_off[base + 2] = excl + v0 + v1;
  if (base + 3 < n) row_off[base + 3] = excl + v0 + v1 + v2;
  if (t == 1023) blksums[blockIdx.x] = sm[1023];
}

__global__ void k_scan2(int* __restrict__ blksums, int nb) {
  if (threadIdx.x == 0 && blockIdx.x == 0) {
    int acc = 0;
    for (int i = 0; i < nb; ++i) { int v = blksums[i]; blksums[i] = acc; acc += v; }
    blksums[nb] = acc;  // total == E
  }
}

// scan finalize + dis = rsqrt(deg+1). cursor[] still holds raw counts here.
__global__ void k_scan3(int* __restrict__ row_off, int* __restrict__ cursor,
                        const int* __restrict__ blksums, float* __restrict__ dis,
                        int n, int nb) {
  int i = blockIdx.x * 1024 + threadIdx.x;
  if (i < n) {
    int c = cursor[i];
    int v = row_off[i] + blksums[i >> 12];
    row_off[i] = v;
    cursor[i] = v;
    dis[i] = rsqrtf((float)c + 1.0f);
  }
  if (i == 0) row_off[n] = blksums[nb];
}

// ---------------------------------------------------------------------------
// k_fill: same 8-group structure; group g scatters only its dst range ->
// csr writes land in a ~800KB window (L2-resident, write-combined).
// csr entry = src only (4B) since dis is folded into the data rows.
// ---------------------------------------------------------------------------
__global__ __launch_bounds__(256) void k_fill(
    const int2* __restrict__ pairs, int* __restrict__ cursor,
    int* __restrict__ csr, ll E, int range, int n) {
  int g = blockIdx.x & (NG - 1);
  int lo = g * range;
  int hi = min(n, lo + range);
  ll tig = (ll)(blockIdx.x >> 3) * 256 + threadIdx.x;
  ll TIG = (ll)(gridDim.x >> 3) * 256;
  for (ll i = tig * 2; i < E; i += TIG * 2) {
    if (i + 1 < E) {
      int4 p = *(const int4*)(pairs + i);
      if (p.y >= lo && p.y < hi) { int pos = atomicAdd(&cursor[p.y], 1); csr[pos] = p.x; }
      if (p.w >= lo && p.w < hi) { int pos = atomicAdd(&cursor[p.w], 1); csr[pos] = p.z; }
    } else {
      int2 p = pairs[i];
      if (p.y >= lo && p.y < hi) { int pos = atomicAdd(&cursor[p.y], 1); csr[pos] = p.x; }
    }
  }
}

// x (f32) -> xb (bf16), pre-scaled by dis[node]; 8 elems/thread
__global__ __launch_bounds__(256) void k_xcast(
    const float* __restrict__ x, const float* __restrict__ dis,
    unsigned short* __restrict__ xb, int total8) {
  int i = blockIdx.x * 256 + threadIdx.x;
  if (i >= total8) return;
  float w = dis[i >> 4];               // 16 chunks of 8 per 128-elem row
  const float4* p = (const float4*)x + (size_t)i * 2;
  float4 a = p[0], b = p[1];
  uint4 o;
  o.x = (uint)f2bf(w * a.x) | ((uint)f2bf(w * a.y) << 16);
  o.y = (uint)f2bf(w * a.z) | ((uint)f2bf(w * a.w) << 16);
  o.z = (uint)f2bf(w * b.x) | ((uint)f2bf(w * b.y) << 16);
  o.w = (uint)f2bf(w * b.z) | ((uint)f2bf(w * b.w) << 16);
  *(uint4*)(xb + (size_t)i * 8) = o;
}

__device__ __forceinline__ void add8(float* a, uint4 r) {
  a[0] += bflo(r.x); a[1] += bfhi(r.x);
  a[2] += bflo(r.y); a[3] += bfhi(r.y);
  a[4] += bflo(r.z); a[5] += bfhi(r.z);
  a[6] += bflo(r.w); a[7] += bfhi(r.w);
}

// ---------------------------------------------------------------------------
// k_fused1: per 16-node tile (256 threads = 4 waves):
//   P1 gather: quarter-wave per node, 8x edge unroll (32 rows in flight/wave);
//      rows pre-scaled by dis[src] -> plain sum, then *di -> bf16 LDS xsb
//   P2 MFMA GEMM1 (agg @ W1) +b1, ReLU -> LDS hsb
//   P3 MFMA GEMM2 (h @ W2) * dis[node] -> xw2b  (pre-scaled for layer 2)
// ---------------------------------------------------------------------------
__global__ __launch_bounds__(256) void k_fused1(
    const unsigned short* __restrict__ xb, const int* __restrict__ csr,
    const int* __restrict__ row_off, const float* __restrict__ dis,
    const unsigned short* __restrict__ w1p, const float* __restrict__ b1,
    const unsigned short* __restrict__ w2p, unsigned short* __restrict__ xw2b,
    int n)
{
  __shared__ __align__(16) unsigned short xsb[16 * 136];  // 4.25KB, 2-way bank stride
  __shared__ __align__(16) unsigned short hsb[16 * 264];  // 8.25KB, 2-way bank stride

  int tid = threadIdx.x;
  int n0 = blockIdx.x * 16;
  int wv = tid >> 6, lane = tid & 63, qq = lane >> 4, l16 = lane & 15;
  int nl = wv * 4 + qq;
  int node = n0 + nl;

  // ---- P1: gather-aggregate (rows pre-scaled by dis[src]) ----
  float a[8] = {0, 0, 0, 0, 0, 0, 0, 0};
  float di = 0.f;
  if (node < n) {
    di = dis[node];
    uint4 v = *((const uint4*)(xb + (size_t)node * FIN) + l16);  // self row
    add8(a, v);
    int e0 = row_off[node], e1 = row_off[node + 1];
    int e = e0;
    for (; e + 8 <= e1; e += 8) {
      int s0 = csr[e],     s1 = csr[e + 1], s2 = csr[e + 2], s3 = csr[e + 3];
      int s4 = csr[e + 4], s5 = csr[e + 5], s6 = csr[e + 6], s7 = csr[e + 7];
      uint4 r0 = *((const uint4*)(xb + (size_t)s0 * FIN) + l16);
      uint4 r1 = *((const uint4*)(xb + (size_t)s1 * FIN) + l16);
      uint4 r2 = *((const uint4*)(xb + (size_t)s2 * FIN) + l16);
      uint4 r3 = *((const uint4*)(xb + (size_t)s3 * FIN) + l16);
      uint4 r4 = *((const uint4*)(xb + (size_t)s4 * FIN) + l16);
      uint4 r5 = *((const uint4*)(xb + (size_t)s5 * FIN) + l16);
      uint4 r6 = *((const uint4*)(xb + (size_t)s6 * FIN) + l16);
      uint4 r7 = *((const uint4*)(xb + (size_t)s7 * FIN) + l16);
      add8(a, r0); add8(a, r1); add8(a, r2); add8(a, r3);
      add8(a, r4); add8(a, r5); add8(a, r6); add8(a, r7);
    }
    for (; e < e1; ++e) {
      uint4 r0 = *((const uint4*)(xb + (size_t)csr[e] * FIN) + l16);
      add8(a, r0);
    }
  }
  {
    uint4 pk;
    pk.x = (uint)f2bf(di * a[0]) | ((uint)f2bf(di * a[1]) << 16);
    pk.y = (uint)f2bf(di * a[2]) | ((uint)f2bf(di * a[3]) << 16);
    pk.z = (uint)f2bf(di * a[4]) | ((uint)f2bf(di * a[5]) << 16);
    pk.w = (uint)f2bf(di * a[6]) | ((uint)f2bf(di * a[7]) << 16);
    *(uint4*)(xsb + nl * 136 + l16 * 8) = pk;
  }
  __syncthreads();

  // ---- P2: MFMA GEMM1 (agg @ W1) ----
  int mrow = lane & 15, g = lane >> 4;
  f32x4 acc1[4] = {{0,0,0,0},{0,0,0,0},{0,0,0,0},{0,0,0,0}};
  #pragma unroll
  for (int s = 0; s < 4; ++s) {
    bf16x8 av = *(const bf16x8*)(xsb + mrow * 136 + s * 32 + g * 8);
    #pragma unroll
    for (int t = 0; t < 4; ++t) {
      int c = wv * 64 + t * 16 + mrow;
      bf16x8 bv = *(const bf16x8*)(w1p + (((size_t)(s * 256 + c) * 4 + g) << 3));
      acc1[t] = __builtin_amdgcn_mfma_f32_16x16x32_bf16(av, bv, acc1[t], 0, 0, 0);
    }
  }
  #pragma unroll
  for (int t = 0; t < 4; ++t) {
    int c = wv * 64 + t * 16 + mrow;
    float bb = b1[c];
    #pragma unroll
    for (int r = 0; r < 4; ++r) {
      float v = fmaxf(acc1[t][r] + bb, 0.f);
      hsb[(g * 4 + r) * 264 + c] = f2bf(v);
    }
  }
  __syncthreads();

  // ---- P3: MFMA GEMM2 (h @ W2), waves 0..2 own col tiles 0..2 ----
  if (wv < 3) {
    f32x4 acc2 = {0, 0, 0, 0};
    int c2 = wv * 16 + mrow;
    #pragma unroll
    for (int s = 0; s < 8; ++s) {
      bf16x8 av = *(const bf16x8*)(hsb + mrow * 264 + s * 32 + g * 8);
      bf16x8 bv = *(const bf16x8*)(w2p + (((size_t)(s * 48 + c2) * 4 + g) << 3));
      acc2 = __builtin_amdgcn_mfma_f32_16x16x32_bf16(av, bv, acc2, 0, 0, 0);
    }
    if (c2 < FOUT) {
      #pragma unroll
      for (int r = 0; r < 4; ++r) {
        int nodeg = n0 + g * 4 + r;
        if (nodeg < n)
          xw2b[((size_t)nodeg << 6) + c2] = f2bf(acc2[r] * dis[nodeg]);
      }
    }
  }
}

// ---------------------------------------------------------------------------
// Layer 2 aggregation + bias + log_softmax. Quarter-wave (16 lanes) per node,
// rows pre-scaled by dis[src]; 8x edge unroll -> 32 rows in flight/wave.
// ---------------------------------------------------------------------------
__global__ __launch_bounds__(256) void k_layer2(
    const unsigned short* __restrict__ xw2b, const int* __restrict__ csr,
    const int* __restrict__ row_off, const float* __restrict__ dis,
    const float* __restrict__ b2, float* __restrict__ out, int n)
{
  int tid = threadIdx.x;
  int node = blockIdx.x * 16 + (tid >> 4);
  int l16 = tid & 15;
  if (node >= n) return;
  float di = dis[node];
  float a0, a1, a2, a3;
  {
    uint2 v = *((const uint2*)(xw2b + ((size_t)node << 6)) + l16);  // self row
    a0 = bflo(v.x); a1 = bfhi(v.x); a2 = bflo(v.y); a3 = bfhi(v.y);
  }
  int e0 = row_off[node], e1 = row_off[node + 1];
  int e = e0;
  for (; e + 8 <= e1; e += 8) {
    int s0 = csr[e],     s1 = csr[e + 1], s2 = csr[e + 2], s3 = csr[e + 3];
    int s4 = csr[e + 4], s5 = csr[e + 5], s6 = csr[e + 6], s7 = csr[e + 7];
    uint2 r0 = *((const uint2*)(xw2b + ((size_t)s0 << 6)) + l16);
    uint2 r1 = *((const uint2*)(xw2b + ((size_t)s1 << 6)) + l16);
    uint2 r2 = *((const uint2*)(xw2b + ((size_t)s2 << 6)) + l16);
    uint2 r3 = *((const uint2*)(xw2b + ((size_t)s3 << 6)) + l16);
    uint2 r4 = *((const uint2*)(xw2b + ((size_t)s4 << 6)) + l16);
    uint2 r5 = *((const uint2*)(xw2b + ((size_t)s5 << 6)) + l16);
    uint2 r6 = *((const uint2*)(xw2b + ((size_t)s6 << 6)) + l16);
    uint2 r7 = *((const uint2*)(xw2b + ((size_t)s7 << 6)) + l16);
    a0 += bflo(r0.x); a1 += bfhi(r0.x); a2 += bflo(r0.y); a3 += bfhi(r0.y);
    a0 += bflo(r1.x); a1 += bfhi(r1.x); a2 += bflo(r1.y); a3 += bfhi(r1.y);
    a0 += bflo(r2.x); a1 += bfhi(r2.x); a2 += bflo(r2.y); a3 += bfhi(r2.y);
    a0 += bflo(r3.x); a1 += bfhi(r3.x); a2 += bflo(r3.y); a3 += bfhi(r3.y);
    a0 += bflo(r4.x); a1 += bfhi(r4.x); a2 += bflo(r4.y); a3 += bfhi(r4.y);
    a0 += bflo(r5.x); a1 += bfhi(r5.x); a2 += bflo(r5.y); a3 += bfhi(r5.y);
    a0 += bflo(r6.x); a1 += bfhi(r6.x); a2 += bflo(r6.y); a3 += bfhi(r6.y);
    a0 += bflo(r7.x); a1 += bfhi(r7.x); a2 += bflo(r7.y); a3 += bfhi(r7.y);
  }
  for (; e < e1; ++e) {
    uint2 r0 = *((const uint2*)(xw2b + ((size_t)csr[e] << 6)) + l16);
    a0 += bflo(r0.x); a1 += bfhi(r0.x); a2 += bflo(r0.y); a3 += bfhi(r0.y);
  }
  // bias + masked 16-lane softmax (cols 4*l16..+3 valid iff l16 < 10)
  bool act = (l16 < 10);
  float l0 = -INFINITY, l1 = -INFINITY, l2 = -INFINITY, l3 = -INFINITY;
  if (act) {
    float4 bv = *(const float4*)(b2 + l16 * 4);
    l0 = di * a0 + bv.x; l1 = di * a1 + bv.y;
    l2 = di * a2 + bv.z; l3 = di * a3 + bv.w;
  }
  float m = fmaxf(fmaxf(l0, l1), fmaxf(l2, l3));
  #pragma unroll
  for (int off = 8; off > 0; off >>= 1) m = fmaxf(m, __shfl_xor(m, off));
  float s = 0.f;
  if (act) s = expf(l0 - m) + expf(l1 - m) + expf(l2 - m) + expf(l3 - m);
  #pragma unroll
  for (int off = 8; off > 0; off >>= 1) s += __shfl_xor(s, off);
  if (act) {
    float ls = m + logf(s);
    float4 o = make_float4(l0 - ls, l1 - ls, l2 - ls, l3 - ls);
    *(float4*)(out + (size_t)node * FOUT + l16 * 4) = o;
  }
}

// ---------------------------------------------------------------------------
extern "C" void kernel_launch(void* const* d_in, const int* in_sizes, int n_in,
                              void* d_out, int out_size, void* d_ws, size_t ws_size,
                              hipStream_t stream) {
  const float* x  = (const float*)d_in[0];
  const void*  ei = d_in[1];
  const float* W1 = (const float*)d_in[2];
  const float* b1 = (const float*)d_in[3];
  const float* W2 = (const float*)d_in[4];
  const float* b2 = (const float*)d_in[5];
  float* out = (float*)d_out;

  int n = in_sizes[0] / FIN;        // 100000
  ll  E = (ll)in_sizes[1] / 2;      // 1600000
  int nb = (n + 4095) / 4096;
  int range = (n + NG - 1) / NG;    // dst-range per group

  char* ws = (char*)d_ws;
  size_t off = 0;
  auto carve = [&](size_t bytes) -> char* {
    char* p = ws + off;
    off = (off + bytes + 255) & ~(size_t)255;
    return p;
  };
  int*   row_off = (int*)carve((size_t)(n + 1) * 4);
  int*   cursor  = (int*)carve((size_t)n * 4);
  int2*  pairs   = (int2*)carve((size_t)E * 8);                        // 12.8 MB
  int*   csr     = (int*)carve((size_t)E * 4);                         // 6.4 MB
  int*   blksums = (int*)carve(64 * 4);
  float* dis     = (float*)carve((size_t)n * 4);
  unsigned short* xb   = (unsigned short*)carve((size_t)n * FIN * 2);  // 25.6 MB
  unsigned short* w1p  = (unsigned short*)carve(32768 * 2);            // 64 KB
  unsigned short* w2p  = (unsigned short*)carve(12288 * 2);            // 24 KB
  unsigned short* xw2b = (unsigned short*)carve((size_t)n * 64 * 2);   // 12.8 MB
  (void)n_in; (void)out_size; (void)ws_size;  // total ~59 MB

  int gn256 = (n + 255) / 256;
  int gx8   = (n * FIN / 8 + 255) / 256;
  int gt16  = (n + 15) / 16;

  hipLaunchKernelGGL(k_init,  dim3(gn256), dim3(256), 0, stream,
                     ei, cursor, W1, W2, w1p, w2p, pairs, n, E);
  hipLaunchKernelGGL(k_count, dim3(512), dim3(256), 0, stream, pairs, cursor, E, range, n);
  hipLaunchKernelGGL(k_scan1, dim3(nb), dim3(1024), 0, stream, cursor, row_off, blksums, n);
  hipLaunchKernelGGL(k_scan2, dim3(1), dim3(1), 0, stream, blksums, nb);
  hipLaunchKernelGGL(k_scan3, dim3((n + 1023) / 1024), dim3(1024), 0, stream,
                     row_off, cursor, blksums, dis, n, nb);
  hipLaunchKernelGGL(k_fill,  dim3(512), dim3(256), 0, stream, pairs, cursor, csr, E, range, n);
  hipLaunchKernelGGL(k_xcast, dim3(gx8), dim3(256), 0, stream, x, dis, xb, n * FIN / 8);
  hipLaunchKernelGGL(k_fused1, dim3(gt16), dim3(256), 0, stream,
                     xb, csr, row_off, dis, w1p, b1, w2p, xw2b, n);
  hipLaunchKernelGGL(k_layer2, dim3(gt16), dim3(256), 0, stream,
                     xw2b, csr, row_off, dis, b2, out, n);
}

// Round 6
// 302.280 us; speedup vs baseline: 3.4427x; 1.0386x over previous
//
#include <hip/hip_runtime.h>
#include <math.h>

typedef long long ll;
typedef unsigned int uint;
typedef __attribute__((ext_vector_type(8))) short bf16x8;
typedef __attribute__((ext_vector_type(4))) float f32x4;

#define FIN 128
#define HID 256
#define FOUT 40
#define NG 8            // dst-range groups for count/fill scatter locality
#define NBIN 64         // degree bins for counting sort
// xw2b rows padded to 64 bf16 (128 B = one L2 line per layer-2 gather)

// ---------------------------------------------------------------------------
// bf16 helpers (manual, deterministic RNE)
// ---------------------------------------------------------------------------
__device__ __forceinline__ float bflo(uint u) { return __uint_as_float(u << 16); }
__device__ __forceinline__ float bfhi(uint u) { return __uint_as_float(u & 0xFFFF0000u); }
__device__ __forceinline__ unsigned short f2bf(float f) {
  uint u = __float_as_uint(f);
  u += 0x7FFFu + ((u >> 16) & 1u);   // round-to-nearest-even
  return (unsigned short)(u >> 16);
}

// int64 vs int32 edge_index: for int64 data the high words of values <100000
// are all zero. ei[1,3,5,7] are hi-words (int64) or src values (int32).
__device__ __forceinline__ int detect64(const uint* __restrict__ ei) {
  return (ei[1] == 0u && ei[3] == 0u && ei[5] == 0u && ei[7] == 0u) ? 1 : 0;
}

// ---------------------------------------------------------------------------
// k_init: zero counters/hist + pack W1,W2 to bf16 B-fragment order +
// pack edge_index into int2 pairs {src,dst} (coalesced).
// B-frag order: wp[((s*C + c)*4 + g)*8 + j] = W[s*32 + g*8 + j][c]
// ---------------------------------------------------------------------------
__global__ __launch_bounds__(256) void k_init(
    const void* __restrict__ ei, int* __restrict__ cnt,
    const float* __restrict__ W1, const float* __restrict__ W2,
    unsigned short* __restrict__ w1p, unsigned short* __restrict__ w2p,
    int2* __restrict__ pairs, int* __restrict__ hist, int n, ll E) {
  int i = blockIdx.x * 256 + threadIdx.x;
  int T = gridDim.x * 256;
  if (i < n) cnt[i] = 0;
  if (i < NBIN) hist[i] = 0;
  if (i < 32768) {                     // W1p: 4 ksteps x 256 cols x 4 g x 8 j
    int j = i & 7, g = (i >> 3) & 3, c = (i >> 5) & 255, s = i >> 13;
    int k = s * 32 + g * 8 + j;
    w1p[i] = f2bf(W1[(size_t)k * HID + c]);
  } else if (i < 32768 + 12288) {      // W2p: 8 ksteps x 48 cols x 4 g x 8 j
    int i2 = i - 32768;
    int j = i2 & 7, g = (i2 >> 3) & 3, q = i2 >> 5;
    int c = q % 48, s = q / 48;
    int k = s * 32 + g * 8 + j;
    w2p[i2] = (c < FOUT) ? f2bf(W2[(size_t)k * FOUT + c]) : (unsigned short)0;
  }
  // edge pack, 4 edges/thread/iter, grid-stride
  int is64 = detect64((const uint*)ei);
  for (ll base = (ll)i * 4; base < E; base += (ll)T * 4) {
    int m = (int)((E - base < 4) ? (E - base) : 4);
    int s[4], d[4];
    if (is64) {
      if (m == 4) {
        longlong2 a0 = *(const longlong2*)((const ll*)ei + base);
        longlong2 a1 = *(const longlong2*)((const ll*)ei + base + 2);
        longlong2 b0 = *(const longlong2*)((const ll*)ei + E + base);
        longlong2 b1 = *(const longlong2*)((const ll*)ei + E + base + 2);
        s[0]=(int)a0.x; s[1]=(int)a0.y; s[2]=(int)a1.x; s[3]=(int)a1.y;
        d[0]=(int)b0.x; d[1]=(int)b0.y; d[2]=(int)b1.x; d[3]=(int)b1.y;
      } else {
        for (int j = 0; j < m; ++j) { s[j]=(int)((const ll*)ei)[base+j]; d[j]=(int)((const ll*)ei)[E+base+j]; }
      }
    } else {
      if (m == 4) {
        int4 a = *(const int4*)((const int*)ei + base);
        int4 b = *(const int4*)((const int*)ei + E + base);
        s[0]=a.x; s[1]=a.y; s[2]=a.z; s[3]=a.w;
        d[0]=b.x; d[1]=b.y; d[2]=b.z; d[3]=b.w;
      } else {
        for (int j = 0; j < m; ++j) { s[j]=((const int*)ei)[base+j]; d[j]=((const int*)ei)[E+base+j]; }
      }
    }
    for (int j = 0; j < m; ++j) pairs[base + j] = make_int2(s[j], d[j]);
  }
}

// ---------------------------------------------------------------------------
// k_count: 8 block-groups; group g histograms only dst in [g*range,(g+1)*range)
// -> all atomics land in an L2-resident 50KB window per group.
// ---------------------------------------------------------------------------
__global__ __launch_bounds__(256) void k_count(
    const int2* __restrict__ pairs, int* __restrict__ cnt, ll E, int range, int n) {
  int g = blockIdx.x & (NG - 1);
  int lo = g * range;
  int hi = min(n, lo + range);
  ll tig = (ll)(blockIdx.x >> 3) * 256 + threadIdx.x;
  ll TIG = (ll)(gridDim.x >> 3) * 256;
  for (ll i = tig * 2; i < E; i += TIG * 2) {
    if (i + 1 < E) {
      int4 p = *(const int4*)(pairs + i);      // {s0,d0,s1,d1}
      if (p.y >= lo && p.y < hi) atomicAdd(&cnt[p.y], 1);
      if (p.w >= lo && p.w < hi) atomicAdd(&cnt[p.w], 1);
    } else {
      int2 p = pairs[i];
      if (p.y >= lo && p.y < hi) atomicAdd(&cnt[p.y], 1);
    }
  }
}

// -------------------- exclusive prefix scan over counts --------------------
__global__ __launch_bounds__(1024) void k_scan1(const int* __restrict__ cnt,
                                                int* __restrict__ row_off,
                                                int* __restrict__ blksums, int n) {
  __shared__ int sm[1024];
  int t = threadIdx.x;
  int base = blockIdx.x * 4096 + t * 4;
  int v0 = (base + 0 < n) ? cnt[base + 0] : 0;
  int v1 = (base + 1 < n) ? cnt[base + 1] : 0;
  int v2 = (base + 2 < n) ? cnt[base + 2] : 0;
  int v3 = (base + 3 < n) ? cnt[base + 3] : 0;
  int s = v0 + v1 + v2 + v3;
  sm[t] = s;
  __syncthreads();
  for (int off = 1; off < 1024; off <<= 1) {
    int u = (t >= off) ? sm[t - off] : 0;
    __syncthreads();
    sm[t] += u;
    __syncthreads();
  }
  int excl = sm[t] - s;
  if (base + 0 < n) row_off[base + 0] = excl;
  if (base + 1 < n) row_off[base + 1] = excl + v0;
  if (base + 2 < n) row_off[base + 2] = excl + v0 + v1;
  if (base + 3 < n) row_off[base + 3] = excl + v0 + v1 + v2;
  if (t == 1023) blksums[blockIdx.x] = sm[1023];
}

__global__ void k_scan2(int* __restrict__ blksums, int nb) {
  if (threadIdx.x == 0 && blockIdx.x == 0) {
    int acc = 0;
    for (int i = 0; i < nb; ++i) { int v = blksums[i]; blksums[i] = acc; acc += v; }
    blksums[nb] = acc;  // total == E
  }
}

// scan finalize + dis = rsqrt(deg+1) + degree histogram (for counting sort).
// cursor[] still holds raw counts here.
__global__ __launch_bounds__(1024) void k_scan3(
    int* __restrict__ row_off, int* __restrict__ cursor,
    const int* __restrict__ blksums, float* __restrict__ dis,
    int* __restrict__ hist, int n, int nb) {
  __shared__ int lh[NBIN];
  int t = threadIdx.x;
  if (t < NBIN) lh[t] = 0;
  __syncthreads();
  int i = blockIdx.x * 1024 + t;
  if (i < n) {
    int c = cursor[i];
    int v = row_off[i] + blksums[i >> 12];
    row_off[i] = v;
    cursor[i] = v;
    dis[i] = rsqrtf((float)c + 1.0f);
    atomicAdd(&lh[min(c, NBIN - 1)], 1);
  }
  if (i == 0) row_off[n] = blksums[nb];
  __syncthreads();
  if (t < NBIN && lh[t]) atomicAdd(&hist[t], lh[t]);
}

// 64-bin exclusive prefix -> bincur (cursor array for the sort scatter)
__global__ void k_binpfx(const int* __restrict__ hist, int* __restrict__ bincur) {
  if (threadIdx.x == 0 && blockIdx.x == 0) {
    int acc = 0;
    for (int b = 0; b < NBIN; ++b) { int v = hist[b]; bincur[b] = acc; acc += v; }
  }
}

// counting-sort scatter: perm[] = node ids in ascending-degree order.
// Order within a bin is nondeterministic but output is permutation-invariant.
__global__ __launch_bounds__(256) void k_perm(
    const int* __restrict__ row_off, int* __restrict__ bincur,
    int* __restrict__ perm, int n) {
  __shared__ int lh[NBIN], lbase[NBIN];
  int t = threadIdx.x;
  if (t < NBIN) lh[t] = 0;
  __syncthreads();
  int base = blockIdx.x * 4096 + t * 16;
  int deg[16];
  #pragma unroll
  for (int j = 0; j < 16; ++j) {
    int i = base + j;
    if (i < n) {
      deg[j] = min(row_off[i + 1] - row_off[i], NBIN - 1);
      atomicAdd(&lh[deg[j]], 1);
    } else deg[j] = -1;
  }
  __syncthreads();
  if (t < NBIN) {
    lbase[t] = lh[t] ? atomicAdd(&bincur[t], lh[t]) : 0;
    lh[t] = 0;
  }
  __syncthreads();
  #pragma unroll
  for (int j = 0; j < 16; ++j) {
    if (deg[j] >= 0) {
      int r = atomicAdd(&lh[deg[j]], 1);
      perm[lbase[deg[j]] + r] = base + j;
    }
  }
}

// ---------------------------------------------------------------------------
// k_fill: 8-group structure; group g scatters only its dst range ->
// csr writes land in a ~800KB window (L2-resident, write-combined).
// ---------------------------------------------------------------------------
__global__ __launch_bounds__(256) void k_fill(
    const int2* __restrict__ pairs, int* __restrict__ cursor,
    int* __restrict__ csr, ll E, int range, int n) {
  int g = blockIdx.x & (NG - 1);
  int lo = g * range;
  int hi = min(n, lo + range);
  ll tig = (ll)(blockIdx.x >> 3) * 256 + threadIdx.x;
  ll TIG = (ll)(gridDim.x >> 3) * 256;
  for (ll i = tig * 2; i < E; i += TIG * 2) {
    if (i + 1 < E) {
      int4 p = *(const int4*)(pairs + i);
      if (p.y >= lo && p.y < hi) { int pos = atomicAdd(&cursor[p.y], 1); csr[pos] = p.x; }
      if (p.w >= lo && p.w < hi) { int pos = atomicAdd(&cursor[p.w], 1); csr[pos] = p.z; }
    } else {
      int2 p = pairs[i];
      if (p.y >= lo && p.y < hi) { int pos = atomicAdd(&cursor[p.y], 1); csr[pos] = p.x; }
    }
  }
}

// x (f32) -> xb (bf16), pre-scaled by dis[node]; 8 elems/thread
__global__ __launch_bounds__(256) void k_xcast(
    const float* __restrict__ x, const float* __restrict__ dis,
    unsigned short* __restrict__ xb, int total8) {
  int i = blockIdx.x * 256 + threadIdx.x;
  if (i >= total8) return;
  float w = dis[i >> 4];               // 16 chunks of 8 per 128-elem row
  const float4* p = (const float4*)x + (size_t)i * 2;
  float4 a = p[0], b = p[1];
  uint4 o;
  o.x = (uint)f2bf(w * a.x) | ((uint)f2bf(w * a.y) << 16);
  o.y = (uint)f2bf(w * a.z) | ((uint)f2bf(w * a.w) << 16);
  o.z = (uint)f2bf(w * b.x) | ((uint)f2bf(w * b.y) << 16);
  o.w = (uint)f2bf(w * b.z) | ((uint)f2bf(w * b.w) << 16);
  *(uint4*)(xb + (size_t)i * 8) = o;
}

__device__ __forceinline__ void add8(float* a, uint4 r) {
  a[0] += bflo(r.x); a[1] += bfhi(r.x);
  a[2] += bflo(r.y); a[3] += bfhi(r.y);
  a[4] += bflo(r.z); a[5] += bfhi(r.z);
  a[6] += bflo(r.w); a[7] += bfhi(r.w);
}

// ---------------------------------------------------------------------------
// k_fused1: per 16-node tile in DEGREE-SORTED order (node = perm[idx]):
//   P1 gather: quarter-wave per node, 8x edge unroll (32 rows in flight/wave);
//      rows pre-scaled by dis[src] -> plain sum, then *di -> bf16 LDS xsb.
//      Sorted order => quarter-waves/waves in a block have equal trip counts.
//   P2 MFMA GEMM1 (agg @ W1) +b1, ReLU -> LDS hsb
//   P3 MFMA GEMM2 (h @ W2) * dis[node] -> xw2b  (pre-scaled for layer 2)
// ---------------------------------------------------------------------------
__global__ __launch_bounds__(256) void k_fused1(
    const unsigned short* __restrict__ xb, const int* __restrict__ csr,
    const int* __restrict__ row_off, const float* __restrict__ dis,
    const int* __restrict__ perm,
    const unsigned short* __restrict__ w1p, const float* __restrict__ b1,
    const unsigned short* __restrict__ w2p, unsigned short* __restrict__ xw2b,
    int n)
{
  __shared__ __align__(16) unsigned short xsb[16 * 136];  // 4.25KB
  __shared__ __align__(16) unsigned short hsb[16 * 264];  // 8.25KB
  __shared__ int   nid[16];
  __shared__ float dsh[16];

  int tid = threadIdx.x;
  int n0 = blockIdx.x * 16;
  int wv = tid >> 6, lane = tid & 63, qq = lane >> 4, l16 = lane & 15;
  int nl = wv * 4 + qq;
  int idx = n0 + nl;
  int node = (idx < n) ? perm[idx] : -1;

  // ---- P1: gather-aggregate (rows pre-scaled by dis[src]) ----
  float a[8] = {0, 0, 0, 0, 0, 0, 0, 0};
  float di = 0.f;
  if (node >= 0) {
    di = dis[node];
    uint4 v = *((const uint4*)(xb + (size_t)node * FIN) + l16);  // self row
    add8(a, v);
    int e0 = row_off[node], e1 = row_off[node + 1];
    int e = e0;
    for (; e + 8 <= e1; e += 8) {
      int s0 = csr[e],     s1 = csr[e + 1], s2 = csr[e + 2], s3 = csr[e + 3];
      int s4 = csr[e + 4], s5 = csr[e + 5], s6 = csr[e + 6], s7 = csr[e + 7];
      uint4 r0 = *((const uint4*)(xb + (size_t)s0 * FIN) + l16);
      uint4 r1 = *((const uint4*)(xb + (size_t)s1 * FIN) + l16);
      uint4 r2 = *((const uint4*)(xb + (size_t)s2 * FIN) + l16);
      uint4 r3 = *((const uint4*)(xb + (size_t)s3 * FIN) + l16);
      uint4 r4 = *((const uint4*)(xb + (size_t)s4 * FIN) + l16);
      uint4 r5 = *((const uint4*)(xb + (size_t)s5 * FIN) + l16);
      uint4 r6 = *((const uint4*)(xb + (size_t)s6 * FIN) + l16);
      uint4 r7 = *((const uint4*)(xb + (size_t)s7 * FIN) + l16);
      add8(a, r0); add8(a, r1); add8(a, r2); add8(a, r3);
      add8(a, r4); add8(a, r5); add8(a, r6); add8(a, r7);
    }
    for (; e < e1; ++e) {
      uint4 r0 = *((const uint4*)(xb + (size_t)csr[e] * FIN) + l16);
      add8(a, r0);
    }
  }
  if (l16 == 0) { nid[nl] = node; dsh[nl] = di; }
  {
    uint4 pk;
    pk.x = (uint)f2bf(di * a[0]) | ((uint)f2bf(di * a[1]) << 16);
    pk.y = (uint)f2bf(di * a[2]) | ((uint)f2bf(di * a[3]) << 16);
    pk.z = (uint)f2bf(di * a[4]) | ((uint)f2bf(di * a[5]) << 16);
    pk.w = (uint)f2bf(di * a[6]) | ((uint)f2bf(di * a[7]) << 16);
    *(uint4*)(xsb + nl * 136 + l16 * 8) = pk;
  }
  __syncthreads();

  // ---- P2: MFMA GEMM1 (agg @ W1) ----
  int mrow = lane & 15, g = lane >> 4;
  f32x4 acc1[4] = {{0,0,0,0},{0,0,0,0},{0,0,0,0},{0,0,0,0}};
  #pragma unroll
  for (int s = 0; s < 4; ++s) {
    bf16x8 av = *(const bf16x8*)(xsb + mrow * 136 + s * 32 + g * 8);
    #pragma unroll
    for (int t = 0; t < 4; ++t) {
      int c = wv * 64 + t * 16 + mrow;
      bf16x8 bv = *(const bf16x8*)(w1p + (((size_t)(s * 256 + c) * 4 + g) << 3));
      acc1[t] = __builtin_amdgcn_mfma_f32_16x16x32_bf16(av, bv, acc1[t], 0, 0, 0);
    }
  }
  #pragma unroll
  for (int t = 0; t < 4; ++t) {
    int c = wv * 64 + t * 16 + mrow;
    float bb = b1[c];
    #pragma unroll
    for (int r = 0; r < 4; ++r) {
      float v = fmaxf(acc1[t][r] + bb, 0.f);
      hsb[(g * 4 + r) * 264 + c] = f2bf(v);
    }
  }
  __syncthreads();

  // ---- P3: MFMA GEMM2 (h @ W2), waves 0..2 own col tiles 0..2 ----
  if (wv < 3) {
    f32x4 acc2 = {0, 0, 0, 0};
    int c2 = wv * 16 + mrow;
    #pragma unroll
    for (int s = 0; s < 8; ++s) {
      bf16x8 av = *(const bf16x8*)(hsb + mrow * 264 + s * 32 + g * 8);
      bf16x8 bv = *(const bf16x8*)(w2p + (((size_t)(s * 48 + c2) * 4 + g) << 3));
      acc2 = __builtin_amdgcn_mfma_f32_16x16x32_bf16(av, bv, acc2, 0, 0, 0);
    }
    if (c2 < FOUT) {
      #pragma unroll
      for (int r = 0; r < 4; ++r) {
        int nodeg = nid[g * 4 + r];
        if (nodeg >= 0)
          xw2b[((size_t)nodeg << 6) + c2] = f2bf(acc2[r] * dsh[g * 4 + r]);
      }
    }
  }
}

// ---------------------------------------------------------------------------
// Layer 2 aggregation + bias + log_softmax, in degree-sorted order.
// Quarter-wave (16 lanes) per node; 8x edge unroll -> 32 rows in flight/wave.
// ---------------------------------------------------------------------------
__global__ __launch_bounds__(256) void k_layer2(
    const unsigned short* __restrict__ xw2b, const int* __restrict__ csr,
    const int* __restrict__ row_off, const float* __restrict__ dis,
    const int* __restrict__ perm,
    const float* __restrict__ b2, float* __restrict__ out, int n)
{
  int tid = threadIdx.x;
  int idx = blockIdx.x * 16 + (tid >> 4);
  int l16 = tid & 15;
  if (idx >= n) return;
  int node = perm[idx];
  float di = dis[node];
  float a0, a1, a2, a3;
  {
    uint2 v = *((const uint2*)(xw2b + ((size_t)node << 6)) + l16);  // self row
    a0 = bflo(v.x); a1 = bfhi(v.x); a2 = bflo(v.y); a3 = bfhi(v.y);
  }
  int e0 = row_off[node], e1 = row_off[node + 1];
  int e = e0;
  for (; e + 8 <= e1; e += 8) {
    int s0 = csr[e],     s1 = csr[e + 1], s2 = csr[e + 2], s3 = csr[e + 3];
    int s4 = csr[e + 4], s5 = csr[e + 5], s6 = csr[e + 6], s7 = csr[e + 7];
    uint2 r0 = *((const uint2*)(xw2b + ((size_t)s0 << 6)) + l16);
    uint2 r1 = *((const uint2*)(xw2b + ((size_t)s1 << 6)) + l16);
    uint2 r2 = *((const uint2*)(xw2b + ((size_t)s2 << 6)) + l16);
    uint2 r3 = *((const uint2*)(xw2b + ((size_t)s3 << 6)) + l16);
    uint2 r4 = *((const uint2*)(xw2b + ((size_t)s4 << 6)) + l16);
    uint2 r5 = *((const uint2*)(xw2b + ((size_t)s5 << 6)) + l16);
    uint2 r6 = *((const uint2*)(xw2b + ((size_t)s6 << 6)) + l16);
    uint2 r7 = *((const uint2*)(xw2b + ((size_t)s7 << 6)) + l16);
    a0 += bflo(r0.x); a1 += bfhi(r0.x); a2 += bflo(r0.y); a3 += bfhi(r0.y);
    a0 += bflo(r1.x); a1 += bfhi(r1.x); a2 += bflo(r1.y); a3 += bfhi(r1.y);
    a0 += bflo(r2.x); a1 += bfhi(r2.x); a2 += bflo(r2.y); a3 += bfhi(r2.y);
    a0 += bflo(r3.x); a1 += bfhi(r3.x); a2 += bflo(r3.y); a3 += bfhi(r3.y);
    a0 += bflo(r4.x); a1 += bfhi(r4.x); a2 += bflo(r4.y); a3 += bfhi(r4.y);
    a0 += bflo(r5.x); a1 += bfhi(r5.x); a2 += bflo(r5.y); a3 += bfhi(r5.y);
    a0 += bflo(r6.x); a1 += bfhi(r6.x); a2 += bflo(r6.y); a3 += bfhi(r6.y);
    a0 += bflo(r7.x); a1 += bfhi(r7.x); a2 += bflo(r7.y); a3 += bfhi(r7.y);
  }
  for (; e < e1; ++e) {
    uint2 r0 = *((const uint2*)(xw2b + ((size_t)csr[e] << 6)) + l16);
    a0 += bflo(r0.x); a1 += bfhi(r0.x); a2 += bflo(r0.y); a3 += bfhi(r0.y);
  }
  // bias + masked 16-lane softmax (cols 4*l16..+3 valid iff l16 < 10)
  bool act = (l16 < 10);
  float l0 = -INFINITY, l1 = -INFINITY, l2 = -INFINITY, l3 = -INFINITY;
  if (act) {
    float4 bv = *(const float4*)(b2 + l16 * 4);
    l0 = di * a0 + bv.x; l1 = di * a1 + bv.y;
    l2 = di * a2 + bv.z; l3 = di * a3 + bv.w;
  }
  float m = fmaxf(fmaxf(l0, l1), fmaxf(l2, l3));
  #pragma unroll
  for (int off = 8; off > 0; off >>= 1) m = fmaxf(m, __shfl_xor(m, off));
  float s = 0.f;
  if (act) s = expf(l0 - m) + expf(l1 - m) + expf(l2 - m) + expf(l3 - m);
  #pragma unroll
  for (int off = 8; off > 0; off >>= 1) s += __shfl_xor(s, off);
  if (act) {
    float ls = m + logf(s);
    float4 o = make_float4(l0 - ls, l1 - ls, l2 - ls, l3 - ls);
    *(float4*)(out + (size_t)node * FOUT + l16 * 4) = o;
  }
}

// ---------------------------------------------------------------------------
extern "C" void kernel_launch(void* const* d_in, const int* in_sizes, int n_in,
                              void* d_out, int out_size, void* d_ws, size_t ws_size,
                              hipStream_t stream) {
  const float* x  = (const float*)d_in[0];
  const void*  ei = d_in[1];
  const float* W1 = (const float*)d_in[2];
  const float* b1 = (const float*)d_in[3];
  const float* W2 = (const float*)d_in[4];
  const float* b2 = (const float*)d_in[5];
  float* out = (float*)d_out;

  int n = in_sizes[0] / FIN;        // 100000
  ll  E = (ll)in_sizes[1] / 2;      // 1600000
  int nb = (n + 4095) / 4096;
  int range = (n + NG - 1) / NG;    // dst-range per group

  char* ws = (char*)d_ws;
  size_t off = 0;
  auto carve = [&](size_t bytes) -> char* {
    char* p = ws + off;
    off = (off + bytes + 255) & ~(size_t)255;
    return p;
  };
  int*   row_off = (int*)carve((size_t)(n + 1) * 4);
  int*   cursor  = (int*)carve((size_t)n * 4);
  int2*  pairs   = (int2*)carve((size_t)E * 8);                        // 12.8 MB
  int*   csr     = (int*)carve((size_t)E * 4);                         // 6.4 MB
  int*   blksums = (int*)carve(64 * 4);
  int*   hist    = (int*)carve(NBIN * 4);
  int*   bincur  = (int*)carve(NBIN * 4);
  int*   perm    = (int*)carve((size_t)n * 4);                         // 400 KB
  float* dis     = (float*)carve((size_t)n * 4);
  unsigned short* xb   = (unsigned short*)carve((size_t)n * FIN * 2);  // 25.6 MB
  unsigned short* w1p  = (unsigned short*)carve(32768 * 2);            // 64 KB
  unsigned short* w2p  = (unsigned short*)carve(12288 * 2);            // 24 KB
  unsigned short* xw2b = (unsigned short*)carve((size_t)n * 64 * 2);   // 12.8 MB
  (void)n_in; (void)out_size; (void)ws_size;  // total ~59 MB

  int gn256 = (n + 255) / 256;
  int gx8   = (n * FIN / 8 + 255) / 256;
  int gt16  = (n + 15) / 16;
  int gperm = (n + 4095) / 4096;

  hipLaunchKernelGGL(k_init,  dim3(gn256), dim3(256), 0, stream,
                     ei, cursor, W1, W2, w1p, w2p, pairs, hist, n, E);
  hipLaunchKernelGGL(k_count, dim3(512), dim3(256), 0, stream, pairs, cursor, E, range, n);
  hipLaunchKernelGGL(k_scan1, dim3(nb), dim3(1024), 0, stream, cursor, row_off, blksums, n);
  hipLaunchKernelGGL(k_scan2, dim3(1), dim3(1), 0, stream, blksums, nb);
  hipLaunchKernelGGL(k_scan3, dim3((n + 1023) / 1024), dim3(1024), 0, stream,
                     row_off, cursor, blksums, dis, hist, n, nb);
  hipLaunchKernelGGL(k_binpfx, dim3(1), dim3(1), 0, stream, hist, bincur);
  hipLaunchKernelGGL(k_perm,  dim3(gperm), dim3(256), 0, stream, row_off, bincur, perm, n);
  hipLaunchKernelGGL(k_fill,  dim3(512), dim3(256), 0, stream, pairs, cursor, csr, E, range, n);
  hipLaunchKernelGGL(k_xcast, dim3(gx8), dim3(256), 0, stream, x, dis, xb, n * FIN / 8);
  hipLaunchKernelGGL(k_fused1, dim3(gt16), dim3(256), 0, stream,
                     xb, csr, row_off, dis, perm, w1p, b1, w2p, xw2b, n);
  hipLaunchKernelGGL(k_layer2, dim3(gt16), dim3(256), 0, stream,
                     xw2b, csr, row_off, dis, perm, b2, out, n);
}

// Round 7
// 300.896 us; speedup vs baseline: 3.4585x; 1.0046x over previous
//
#include <hip/hip_runtime.h>
#include <math.h>

typedef long long ll;
typedef unsigned int uint;
typedef __attribute__((ext_vector_type(8))) short bf16x8;
typedef __attribute__((ext_vector_type(4))) float f32x4;

#define FIN 128
#define HID 256
#define FOUT 40
#define NG 8            // dst-range groups for fill scatter locality
#define NBIN 64         // degree bins for counting sort
// xw2b rows are tight 40 bf16 = 80 B (always exactly 2 cache lines)

// ---------------------------------------------------------------------------
// bf16 helpers (manual, deterministic RNE)
// ---------------------------------------------------------------------------
__device__ __forceinline__ float bflo(uint u) { return __uint_as_float(u << 16); }
__device__ __forceinline__ float bfhi(uint u) { return __uint_as_float(u & 0xFFFF0000u); }
__device__ __forceinline__ unsigned short f2bf(float f) {
  uint u = __float_as_uint(f);
  u += 0x7FFFu + ((u >> 16) & 1u);   // round-to-nearest-even
  return (unsigned short)(u >> 16);
}

// int64 vs int32 edge_index: for int64 data the high words of values <100000
// are all zero. ei[1,3,5,7] are hi-words (int64) or src values (int32).
__device__ __forceinline__ int detect64(const uint* __restrict__ ei) {
  return (ei[1] == 0u && ei[3] == 0u && ei[5] == 0u && ei[7] == 0u) ? 1 : 0;
}

// ---------------------------------------------------------------------------
// k_init: pack W1,W2 to bf16 B-fragment order + pack edge_index into int2
// pairs {src,dst} + degree histogram via plain global atomics (cnt pre-zeroed
// by memset). Grid 2048 blocks so the 38 MB of edge traffic saturates.
// B-frag order: wp[((s*C + c)*4 + g)*8 + j] = W[s*32 + g*8 + j][c]
// ---------------------------------------------------------------------------
__global__ __launch_bounds__(256) void k_init(
    const void* __restrict__ ei, int* __restrict__ cnt,
    const float* __restrict__ W1, const float* __restrict__ W2,
    unsigned short* __restrict__ w1p, unsigned short* __restrict__ w2p,
    int2* __restrict__ pairs, ll E) {
  int i = blockIdx.x * 256 + threadIdx.x;
  int T = gridDim.x * 256;
  if (i < 32768) {                     // W1p: 4 ksteps x 256 cols x 4 g x 8 j
    int j = i & 7, g = (i >> 3) & 3, c = (i >> 5) & 255, s = i >> 13;
    int k = s * 32 + g * 8 + j;
    w1p[i] = f2bf(W1[(size_t)k * HID + c]);
  } else if (i < 32768 + 12288) {      // W2p: 8 ksteps x 48 cols x 4 g x 8 j
    int i2 = i - 32768;
    int j = i2 & 7, g = (i2 >> 3) & 3, q = i2 >> 5;
    int c = q % 48, s = q / 48;
    int k = s * 32 + g * 8 + j;
    w2p[i2] = (c < FOUT) ? f2bf(W2[(size_t)k * FOUT + c]) : (unsigned short)0;
  }
  // edge pack + degree histogram, 4 edges/thread/iter, grid-stride
  int is64 = detect64((const uint*)ei);
  for (ll base = (ll)i * 4; base < E; base += (ll)T * 4) {
    int m = (int)((E - base < 4) ? (E - base) : 4);
    int s[4], d[4];
    if (is64) {
      if (m == 4) {
        longlong2 a0 = *(const longlong2*)((const ll*)ei + base);
        longlong2 a1 = *(const longlong2*)((const ll*)ei + base + 2);
        longlong2 b0 = *(const longlong2*)((const ll*)ei + E + base);
        longlong2 b1 = *(const longlong2*)((const ll*)ei + E + base + 2);
        s[0]=(int)a0.x; s[1]=(int)a0.y; s[2]=(int)a1.x; s[3]=(int)a1.y;
        d[0]=(int)b0.x; d[1]=(int)b0.y; d[2]=(int)b1.x; d[3]=(int)b1.y;
      } else {
        for (int j = 0; j < m; ++j) { s[j]=(int)((const ll*)ei)[base+j]; d[j]=(int)((const ll*)ei)[E+base+j]; }
      }
    } else {
      if (m == 4) {
        int4 a = *(const int4*)((const int*)ei + base);
        int4 b = *(const int4*)((const int*)ei + E + base);
        s[0]=a.x; s[1]=a.y; s[2]=a.z; s[3]=a.w;
        d[0]=b.x; d[1]=b.y; d[2]=b.z; d[3]=b.w;
      } else {
        for (int j = 0; j < m; ++j) { s[j]=((const int*)ei)[base+j]; d[j]=((const int*)ei)[E+base+j]; }
      }
    }
    if (m == 4) {
      *(int4*)(pairs + base)     = make_int4(s[0], d[0], s[1], d[1]);
      *(int4*)(pairs + base + 2) = make_int4(s[2], d[2], s[3], d[3]);
    } else {
      for (int j = 0; j < m; ++j) pairs[base + j] = make_int2(s[j], d[j]);
    }
    for (int j = 0; j < m; ++j) atomicAdd(&cnt[d[j]], 1);
  }
}

// -------------------- exclusive prefix scan over counts --------------------
__global__ __launch_bounds__(1024) void k_scan1(const int* __restrict__ cnt,
                                                int* __restrict__ row_off,
                                                int* __restrict__ blksums, int n) {
  __shared__ int sm[1024];
  int t = threadIdx.x;
  int base = blockIdx.x * 4096 + t * 4;
  int v0 = (base + 0 < n) ? cnt[base + 0] : 0;
  int v1 = (base + 1 < n) ? cnt[base + 1] : 0;
  int v2 = (base + 2 < n) ? cnt[base + 2] : 0;
  int v3 = (base + 3 < n) ? cnt[base + 3] : 0;
  int s = v0 + v1 + v2 + v3;
  sm[t] = s;
  __syncthreads();
  for (int off = 1; off < 1024; off <<= 1) {
    int u = (t >= off) ? sm[t - off] : 0;
    __syncthreads();
    sm[t] += u;
    __syncthreads();
  }
  int excl = sm[t] - s;
  if (base + 0 < n) row_off[base + 0] = excl;
  if (base + 1 < n) row_off[base + 1] = excl + v0;
  if (base + 2 < n) row_off[base + 2] = excl + v0 + v1;
  if (base + 3 < n) row_off[base + 3] = excl + v0 + v1 + v2;
  if (t == 1023) blksums[blockIdx.x] = sm[1023];
}

__global__ void k_scan2(int* __restrict__ blksums, int nb) {
  if (threadIdx.x == 0 && blockIdx.x == 0) {
    int acc = 0;
    for (int i = 0; i < nb; ++i) { int v = blksums[i]; blksums[i] = acc; acc += v; }
    blksums[nb] = acc;  // total == E
  }
}

// scan finalize + dis = rsqrt(deg+1) + degree histogram (for counting sort).
// cursor[] still holds raw counts here (hist pre-zeroed by memset).
__global__ __launch_bounds__(1024) void k_scan3(
    int* __restrict__ row_off, int* __restrict__ cursor,
    const int* __restrict__ blksums, float* __restrict__ dis,
    int* __restrict__ hist, int n, int nb) {
  __shared__ int lh[NBIN];
  int t = threadIdx.x;
  if (t < NBIN) lh[t] = 0;
  __syncthreads();
  int i = blockIdx.x * 1024 + t;
  if (i < n) {
    int c = cursor[i];
    int v = row_off[i] + blksums[i >> 12];
    row_off[i] = v;
    cursor[i] = v;
    dis[i] = rsqrtf((float)c + 1.0f);
    atomicAdd(&lh[min(c, NBIN - 1)], 1);
  }
  if (i == 0) row_off[n] = blksums[nb];
  __syncthreads();
  if (t < NBIN && lh[t]) atomicAdd(&hist[t], lh[t]);
}

// 64-bin exclusive prefix -> bincur (cursor array for the sort scatter)
__global__ void k_binpfx(const int* __restrict__ hist, int* __restrict__ bincur) {
  if (threadIdx.x == 0 && blockIdx.x == 0) {
    int acc = 0;
    for (int b = 0; b < NBIN; ++b) { int v = hist[b]; bincur[b] = acc; acc += v; }
  }
}

// counting-sort scatter: perm[] = node ids in ascending-degree order.
// Order within a bin is nondeterministic but output is permutation-invariant
// (tolerance-validated; each node's row is computed identically).
__global__ __launch_bounds__(256) void k_perm(
    const int* __restrict__ row_off, int* __restrict__ bincur,
    int* __restrict__ perm, int n) {
  __shared__ int lh[NBIN], lbase[NBIN];
  int t = threadIdx.x;
  if (t < NBIN) lh[t] = 0;
  __syncthreads();
  int base = blockIdx.x * 4096 + t * 16;
  int deg[16];
  #pragma unroll
  for (int j = 0; j < 16; ++j) {
    int i = base + j;
    if (i < n) {
      deg[j] = min(row_off[i + 1] - row_off[i], NBIN - 1);
      atomicAdd(&lh[deg[j]], 1);
    } else deg[j] = -1;
  }
  __syncthreads();
  if (t < NBIN) {
    lbase[t] = lh[t] ? atomicAdd(&bincur[t], lh[t]) : 0;
    lh[t] = 0;
  }
  __syncthreads();
  #pragma unroll
  for (int j = 0; j < 16; ++j) {
    if (deg[j] >= 0) {
      int r = atomicAdd(&lh[deg[j]], 1);
      perm[lbase[deg[j]] + r] = base + j;
    }
  }
}

// ---------------------------------------------------------------------------
// k_fill: 8-group structure; group g scatters only its dst range ->
// csr writes land in a ~800KB window (L2-resident, write-combined).
// Grid 2048 (256 blocks/group) — the pairs re-reads are L3-resident.
// ---------------------------------------------------------------------------
__global__ __launch_bounds__(256) void k_fill(
    const int2* __restrict__ pairs, int* __restrict__ cursor,
    int* __restrict__ csr, ll E, int range, int n) {
  int g = blockIdx.x & (NG - 1);
  int lo = g * range;
  int hi = min(n, lo + range);
  ll tig = (ll)(blockIdx.x >> 3) * 256 + threadIdx.x;
  ll TIG = (ll)(gridDim.x >> 3) * 256;
  for (ll i = tig * 2; i < E; i += TIG * 2) {
    if (i + 1 < E) {
      int4 p = *(const int4*)(pairs + i);
      if (p.y >= lo && p.y < hi) { int pos = atomicAdd(&cursor[p.y], 1); csr[pos] = p.x; }
      if (p.w >= lo && p.w < hi) { int pos = atomicAdd(&cursor[p.w], 1); csr[pos] = p.z; }
    } else {
      int2 p = pairs[i];
      if (p.y >= lo && p.y < hi) { int pos = atomicAdd(&cursor[p.y], 1); csr[pos] = p.x; }
    }
  }
}

// x (f32) -> xb (bf16), pre-scaled by dis[node]; 8 elems/thread
__global__ __launch_bounds__(256) void k_xcast(
    const float* __restrict__ x, const float* __restrict__ dis,
    unsigned short* __restrict__ xb, int total8) {
  int i = blockIdx.x * 256 + threadIdx.x;
  if (i >= total8) return;
  float w = dis[i >> 4];               // 16 chunks of 8 per 128-elem row
  const float4* p = (const float4*)x + (size_t)i * 2;
  float4 a = p[0], b = p[1];
  uint4 o;
  o.x = (uint)f2bf(w * a.x) | ((uint)f2bf(w * a.y) << 16);
  o.y = (uint)f2bf(w * a.z) | ((uint)f2bf(w * a.w) << 16);
  o.z = (uint)f2bf(w * b.x) | ((uint)f2bf(w * b.y) << 16);
  o.w = (uint)f2bf(w * b.z) | ((uint)f2bf(w * b.w) << 16);
  *(uint4*)(xb + (size_t)i * 8) = o;
}

__device__ __forceinline__ void add8(float* a, uint4 r) {
  a[0] += bflo(r.x); a[1] += bfhi(r.x);
  a[2] += bflo(r.y); a[3] += bfhi(r.y);
  a[4] += bflo(r.z); a[5] += bfhi(r.z);
  a[6] += bflo(r.w); a[7] += bfhi(r.w);
}

// ---------------------------------------------------------------------------
// k_fused1: per 16-node tile in DEGREE-SORTED order (node = perm[idx]):
//   P1 gather: quarter-wave per node, 8x edge unroll (32 rows in flight/wave);
//      rows pre-scaled by dis[src] -> plain sum, then *di -> bf16 LDS xsb.
//   P2 MFMA GEMM1 (agg @ W1) +b1, ReLU -> LDS hsb
//   P3 MFMA GEMM2 (h @ W2) * dis[node] -> xw2b (80B rows, pre-scaled for L2)
// ---------------------------------------------------------------------------
__global__ __launch_bounds__(256) void k_fused1(
    const unsigned short* __restrict__ xb, const int* __restrict__ csr,
    const int* __restrict__ row_off, const float* __restrict__ dis,
    const int* __restrict__ perm,
    const unsigned short* __restrict__ w1p, const float* __restrict__ b1,
    const unsigned short* __restrict__ w2p, unsigned short* __restrict__ xw2b,
    int n)
{
  __shared__ __align__(16) unsigned short xsb[16 * 136];  // 4.25KB
  __shared__ __align__(16) unsigned short hsb[16 * 264];  // 8.25KB
  __shared__ int   nid[16];
  __shared__ float dsh[16];

  int tid = threadIdx.x;
  int n0 = blockIdx.x * 16;
  int wv = tid >> 6, lane = tid & 63, qq = lane >> 4, l16 = lane & 15;
  int nl = wv * 4 + qq;
  int idx = n0 + nl;
  int node = (idx < n) ? perm[idx] : -1;

  // ---- P1: gather-aggregate (rows pre-scaled by dis[src]) ----
  float a[8] = {0, 0, 0, 0, 0, 0, 0, 0};
  float di = 0.f;
  if (node >= 0) {
    di = dis[node];
    uint4 v = *((const uint4*)(xb + (size_t)node * FIN) + l16);  // self row
    add8(a, v);
    int e0 = row_off[node], e1 = row_off[node + 1];
    int e = e0;
    for (; e + 8 <= e1; e += 8) {
      int s0 = csr[e],     s1 = csr[e + 1], s2 = csr[e + 2], s3 = csr[e + 3];
      int s4 = csr[e + 4], s5 = csr[e + 5], s6 = csr[e + 6], s7 = csr[e + 7];
      uint4 r0 = *((const uint4*)(xb + (size_t)s0 * FIN) + l16);
      uint4 r1 = *((const uint4*)(xb + (size_t)s1 * FIN) + l16);
      uint4 r2 = *((const uint4*)(xb + (size_t)s2 * FIN) + l16);
      uint4 r3 = *((const uint4*)(xb + (size_t)s3 * FIN) + l16);
      uint4 r4 = *((const uint4*)(xb + (size_t)s4 * FIN) + l16);
      uint4 r5 = *((const uint4*)(xb + (size_t)s5 * FIN) + l16);
      uint4 r6 = *((const uint4*)(xb + (size_t)s6 * FIN) + l16);
      uint4 r7 = *((const uint4*)(xb + (size_t)s7 * FIN) + l16);
      add8(a, r0); add8(a, r1); add8(a, r2); add8(a, r3);
      add8(a, r4); add8(a, r5); add8(a, r6); add8(a, r7);
    }
    for (; e < e1; ++e) {
      uint4 r0 = *((const uint4*)(xb + (size_t)csr[e] * FIN) + l16);
      add8(a, r0);
    }
  }
  if (l16 == 0) { nid[nl] = node; dsh[nl] = di; }
  {
    uint4 pk;
    pk.x = (uint)f2bf(di * a[0]) | ((uint)f2bf(di * a[1]) << 16);
    pk.y = (uint)f2bf(di * a[2]) | ((uint)f2bf(di * a[3]) << 16);
    pk.z = (uint)f2bf(di * a[4]) | ((uint)f2bf(di * a[5]) << 16);
    pk.w = (uint)f2bf(di * a[6]) | ((uint)f2bf(di * a[7]) << 16);
    *(uint4*)(xsb + nl * 136 + l16 * 8) = pk;
  }
  __syncthreads();

  // ---- P2: MFMA GEMM1 (agg @ W1) ----
  int mrow = lane & 15, g = lane >> 4;
  f32x4 acc1[4] = {{0,0,0,0},{0,0,0,0},{0,0,0,0},{0,0,0,0}};
  #pragma unroll
  for (int s = 0; s < 4; ++s) {
    bf16x8 av = *(const bf16x8*)(xsb + mrow * 136 + s * 32 + g * 8);
    #pragma unroll
    for (int t = 0; t < 4; ++t) {
      int c = wv * 64 + t * 16 + mrow;
      bf16x8 bv = *(const bf16x8*)(w1p + (((size_t)(s * 256 + c) * 4 + g) << 3));
      acc1[t] = __builtin_amdgcn_mfma_f32_16x16x32_bf16(av, bv, acc1[t], 0, 0, 0);
    }
  }
  #pragma unroll
  for (int t = 0; t < 4; ++t) {
    int c = wv * 64 + t * 16 + mrow;
    float bb = b1[c];
    #pragma unroll
    for (int r = 0; r < 4; ++r) {
      float v = fmaxf(acc1[t][r] + bb, 0.f);
      hsb[(g * 4 + r) * 264 + c] = f2bf(v);
    }
  }
  __syncthreads();

  // ---- P3: MFMA GEMM2 (h @ W2), waves 0..2 own col tiles 0..2 ----
  if (wv < 3) {
    f32x4 acc2 = {0, 0, 0, 0};
    int c2 = wv * 16 + mrow;
    #pragma unroll
    for (int s = 0; s < 8; ++s) {
      bf16x8 av = *(const bf16x8*)(hsb + mrow * 264 + s * 32 + g * 8);
      bf16x8 bv = *(const bf16x8*)(w2p + (((size_t)(s * 48 + c2) * 4 + g) << 3));
      acc2 = __builtin_amdgcn_mfma_f32_16x16x32_bf16(av, bv, acc2, 0, 0, 0);
    }
    if (c2 < FOUT) {
      #pragma unroll
      for (int r = 0; r < 4; ++r) {
        int nodeg = nid[g * 4 + r];
        if (nodeg >= 0)
          xw2b[(size_t)nodeg * FOUT + c2] = f2bf(acc2[r] * dsh[g * 4 + r]);
      }
    }
  }
}

// ---------------------------------------------------------------------------
// Layer 2 aggregation + bias + log_softmax, in degree-sorted order.
// Quarter-wave per node; rows are tight 80B (lanes 0..9 load uint2 each);
// 8x edge unroll -> up to 32 rows in flight/wave.
// ---------------------------------------------------------------------------
__global__ __launch_bounds__(256) void k_layer2(
    const unsigned short* __restrict__ xw2b, const int* __restrict__ csr,
    const int* __restrict__ row_off, const float* __restrict__ dis,
    const int* __restrict__ perm,
    const float* __restrict__ b2, float* __restrict__ out, int n)
{
  int tid = threadIdx.x;
  int idx = blockIdx.x * 16 + (tid >> 4);
  int l16 = tid & 15;
  if (idx >= n) return;
  int node = perm[idx];
  float di = dis[node];
  bool act = (l16 < 10);
  float a0 = 0.f, a1 = 0.f, a2 = 0.f, a3 = 0.f;
  if (act) {
    uint2 v = *((const uint2*)(xw2b + (size_t)node * FOUT) + l16);  // self row
    a0 = bflo(v.x); a1 = bfhi(v.x); a2 = bflo(v.y); a3 = bfhi(v.y);
  }
  int e0 = row_off[node], e1 = row_off[node + 1];
  int e = e0;
  for (; e + 8 <= e1; e += 8) {
    int s0 = csr[e],     s1 = csr[e + 1], s2 = csr[e + 2], s3 = csr[e + 3];
    int s4 = csr[e + 4], s5 = csr[e + 5], s6 = csr[e + 6], s7 = csr[e + 7];
    if (act) {
      uint2 r0 = *((const uint2*)(xw2b + (size_t)s0 * FOUT) + l16);
      uint2 r1 = *((const uint2*)(xw2b + (size_t)s1 * FOUT) + l16);
      uint2 r2 = *((const uint2*)(xw2b + (size_t)s2 * FOUT) + l16);
      uint2 r3 = *((const uint2*)(xw2b + (size_t)s3 * FOUT) + l16);
      uint2 r4 = *((const uint2*)(xw2b + (size_t)s4 * FOUT) + l16);
      uint2 r5 = *((const uint2*)(xw2b + (size_t)s5 * FOUT) + l16);
      uint2 r6 = *((const uint2*)(xw2b + (size_t)s6 * FOUT) + l16);
      uint2 r7 = *((const uint2*)(xw2b + (size_t)s7 * FOUT) + l16);
      a0 += bflo(r0.x); a1 += bfhi(r0.x); a2 += bflo(r0.y); a3 += bfhi(r0.y);
      a0 += bflo(r1.x); a1 += bfhi(r1.x); a2 += bflo(r1.y); a3 += bfhi(r1.y);
      a0 += bflo(r2.x); a1 += bfhi(r2.x); a2 += bflo(r2.y); a3 += bfhi(r2.y);
      a0 += bflo(r3.x); a1 += bfhi(r3.x); a2 += bflo(r3.y); a3 += bfhi(r3.y);
      a0 += bflo(r4.x); a1 += bfhi(r4.x); a2 += bflo(r4.y); a3 += bfhi(r4.y);
      a0 += bflo(r5.x); a1 += bfhi(r5.x); a2 += bflo(r5.y); a3 += bfhi(r5.y);
      a0 += bflo(r6.x); a1 += bfhi(r6.x); a2 += bflo(r6.y); a3 += bfhi(r6.y);
      a0 += bflo(r7.x); a1 += bfhi(r7.x); a2 += bflo(r7.y); a3 += bfhi(r7.y);
    }
  }
  for (; e < e1; ++e) {
    int s0 = csr[e];
    if (act) {
      uint2 r0 = *((const uint2*)(xw2b + (size_t)s0 * FOUT) + l16);
      a0 += bflo(r0.x); a1 += bfhi(r0.x); a2 += bflo(r0.y); a3 += bfhi(r0.y);
    }
  }
  // bias + masked 16-lane softmax (cols 4*l16..+3 valid iff l16 < 10)
  float l0 = -INFINITY, l1 = -INFINITY, l2 = -INFINITY, l3 = -INFINITY;
  if (act) {
    float4 bv = *(const float4*)(b2 + l16 * 4);
    l0 = di * a0 + bv.x; l1 = di * a1 + bv.y;
    l2 = di * a2 + bv.z; l3 = di * a3 + bv.w;
  }
  float m = fmaxf(fmaxf(l0, l1), fmaxf(l2, l3));
  #pragma unroll
  for (int off = 8; off > 0; off >>= 1) m = fmaxf(m, __shfl_xor(m, off));
  float s = 0.f;
  if (act) s = expf(l0 - m) + expf(l1 - m) + expf(l2 - m) + expf(l3 - m);
  #pragma unroll
  for (int off = 8; off > 0; off >>= 1) s += __shfl_xor(s, off);
  if (act) {
    float ls = m + logf(s);
    float4 o = make_float4(l0 - ls, l1 - ls, l2 - ls, l3 - ls);
    *(float4*)(out + (size_t)node * FOUT + l16 * 4) = o;
  }
}

// ---------------------------------------------------------------------------
extern "C" void kernel_launch(void* const* d_in, const int* in_sizes, int n_in,
                              void* d_out, int out_size, void* d_ws, size_t ws_size,
                              hipStream_t stream) {
  const float* x  = (const float*)d_in[0];
  const void*  ei = d_in[1];
  const float* W1 = (const float*)d_in[2];
  const float* b1 = (const float*)d_in[3];
  const float* W2 = (const float*)d_in[4];
  const float* b2 = (const float*)d_in[5];
  float* out = (float*)d_out;

  int n = in_sizes[0] / FIN;        // 100000
  ll  E = (ll)in_sizes[1] / 2;      // 1600000
  int nb = (n + 4095) / 4096;
  int range = (n + NG - 1) / NG;    // dst-range per group

  char* ws = (char*)d_ws;
  size_t off = 0;
  auto carve = [&](size_t bytes) -> char* {
    char* p = ws + off;
    off = (off + bytes + 255) & ~(size_t)255;
    return p;
  };
  int*   row_off = (int*)carve((size_t)(n + 1) * 4);
  int*   cursor  = (int*)carve((size_t)n * 4);
  int2*  pairs   = (int2*)carve((size_t)E * 8);                        // 12.8 MB
  int*   csr     = (int*)carve((size_t)E * 4);                         // 6.4 MB
  int*   blksums = (int*)carve(64 * 4);
  int*   hist    = (int*)carve(NBIN * 4);
  int*   bincur  = (int*)carve(NBIN * 4);
  int*   perm    = (int*)carve((size_t)n * 4);                         // 400 KB
  float* dis     = (float*)carve((size_t)n * 4);
  unsigned short* xb   = (unsigned short*)carve((size_t)n * FIN * 2);  // 25.6 MB
  unsigned short* w1p  = (unsigned short*)carve(32768 * 2);            // 64 KB
  unsigned short* w2p  = (unsigned short*)carve(12288 * 2);            // 24 KB
  unsigned short* xw2b = (unsigned short*)carve((size_t)n * FOUT * 2); // 8 MB
  (void)n_in; (void)out_size; (void)ws_size;  // total ~55 MB

  int gx8  = (n * FIN / 8 + 255) / 256;
  int gt16 = (n + 15) / 16;
  int gperm = (n + 4095) / 4096;

  // zero degree counters + histogram via capturable memset nodes
  hipMemsetAsync(cursor, 0, (size_t)n * 4, stream);
  hipMemsetAsync(hist, 0, NBIN * 4, stream);

  hipLaunchKernelGGL(k_init,  dim3(2048), dim3(256), 0, stream,
                     ei, cursor, W1, W2, w1p, w2p, pairs, E);
  hipLaunchKernelGGL(k_scan1, dim3(nb), dim3(1024), 0, stream, cursor, row_off, blksums, n);
  hipLaunchKernelGGL(k_scan2, dim3(1), dim3(1), 0, stream, blksums, nb);
  hipLaunchKernelGGL(k_scan3, dim3((n + 1023) / 1024), dim3(1024), 0, stream,
                     row_off, cursor, blksums, dis, hist, n, nb);
  hipLaunchKernelGGL(k_binpfx, dim3(1), dim3(1), 0, stream, hist, bincur);
  hipLaunchKernelGGL(k_perm,  dim3(gperm), dim3(256), 0, stream, row_off, bincur, perm, n);
  hipLaunchKernelGGL(k_fill,  dim3(2048), dim3(256), 0, stream, pairs, cursor, csr, E, range, n);
  hipLaunchKernelGGL(k_xcast, dim3(gx8), dim3(256), 0, stream, x, dis, xb, n * FIN / 8);
  hipLaunchKernelGGL(k_fused1, dim3(gt16), dim3(256), 0, stream,
                     xb, csr, row_off, dis, perm, w1p, b1, w2p, xw2b, n);
  hipLaunchKernelGGL(k_layer2, dim3(gt16), dim3(256), 0, stream,
                     xw2b, csr, row_off, dis, perm, b2, out, n);
}